// Round 14
// baseline (397.407 us; speedup 1.0000x reference)
//
#include <hip/hip_runtime.h>

// ============================================================================
// FastRCNN Relation FC Head, MI355X round 14.
// vs round 13 (383us): gemm8p rebuilt as a 3-STAGE deep pipeline:
// 256x256 tile, BK=32, 3 x 32KB LDS buffers (96KB), loads issued 2 tiles
// ahead (window >= 1 full tile > HBM latency), ONE barrier per tile,
// exact-FIFO counted vmcnt (10 / 6 / 0 tail peel; never drains in steady
// state).  Swizzle for 64B rows: byte ^= ((row>>1)&3)<<4 (frag reads
// <=2-way).  Two static A-reg sets (2x unrolled loop).  All else frozen.
// ============================================================================

using bf16x8 = __attribute__((ext_vector_type(8))) short;
using f32x4  = __attribute__((ext_vector_type(4))) float;
typedef unsigned short u16;
typedef unsigned int   u32;

#define DEV __device__ __forceinline__

DEV u32 cvtpk(float lo, float hi) {          // 2x fp32 -> packed bf16 (1 instr)
  u32 r;
  asm("v_cvt_pk_bf16_f32 %0, %1, %2" : "=v"(r) : "v"(lo), "v"(hi));
  return r;
}
DEV u16 f2bf(float f) { return (u16)cvtpk(f, f); }
DEV float bf2f(u16 h) { return __uint_as_float(((u32)h) << 16); }

DEV f32x4 mfma16(bf16x8 a, bf16x8 b, f32x4 c) {
  return __builtin_amdgcn_mfma_f32_16x16x32_bf16(a, b, c, 0, 0, 0);
}
DEV void gload16(const u16* g, u16* l) {
  __builtin_amdgcn_global_load_lds((const __attribute__((address_space(1))) void*)g,
                                   (__attribute__((address_space(3))) void*)l, 16, 0, 0);
}

DEV void fsincos(float x, float* s, float* c) {
  float r = x * 0.15915494309189535f;   // revolutions, exact-identity reduction
  r -= rintf(r);
  float a = r * 6.283185307179586f;
  *s = __sinf(a); *c = __cosf(a);
}

__constant__ float C100D[8] = {100.f, 42.16965034285822f, 17.78279410038923f,
                               7.498942093324559f, 3.1622776601683795f,
                               1.333521432163324f, 0.5623413251903491f,
                               0.23713737056616552f};

// ---------------------------------------------------------------------------
// prep: weight converts/transposes only (unchanged).
// ---------------------------------------------------------------------------
struct PrepArgs {
  const float* Wo1; u16* Wo1_b;
  const float* Wo2; u16* Wo2_b;
  const float* Wfc1; u16* Wfc1_t;
  const float* wsrc[5]; u16* wdst[5];
};

__global__ __launch_bounds__(256) void prep_kernel(PrepArgs p) {
  __shared__ float tp[32][36];
  int b = blockIdx.x, tid = threadIdx.x;
  if (b < 1024) {                               // plain converts (1024^2 each)
    const float* src = (b < 512) ? p.Wo1 : p.Wo2;
    u16* dst = (b < 512) ? p.Wo1_b : p.Wo2_b;
    size_t i = ((size_t)(b & 511) * 256 + tid) * 8;
    float4 a = *(const float4*)(src + i);
    float4 c = *(const float4*)(src + i + 4);
    int4 v;
    v.x = (int)cvtpk(a.x, a.y); v.y = (int)cvtpk(a.z, a.w);
    v.z = (int)cvtpk(c.x, c.y); v.w = (int)cvtpk(c.z, c.w);
    *(int4*)(dst + i) = v;
    return;
  }
  const float* in; u16* out; int r0, c0, R, C;
  if (b < 13568) {
    int idx = b - 1024;
    in = p.Wfc1; out = p.Wfc1_t; R = 12544; C = 1024;
    r0 = (idx >> 5) * 32; c0 = (idx & 31) * 32;
  } else {
    int idx = b - 13568;
    int z = idx >> 10, rest = idx & 1023;
    in = p.wsrc[z]; out = p.wdst[z]; R = 1024; C = 1024;
    r0 = (rest >> 5) * 32; c0 = (rest & 31) * 32;
  }
  {                                             // 32x32 vectorized transpose
    int r = tid >> 3, c4 = (tid & 7) * 4;
    float4 v = *(const float4*)(in + (size_t)(r0 + r) * C + c0 + c4);
    *(float4*)&tp[r][c4] = v;
  }
  __syncthreads();
  {
    int c = tid >> 3, r4 = (tid & 7) * 4;
    int2 v;
    v.x = (int)cvtpk(tp[r4 + 0][c], tp[r4 + 1][c]);
    v.y = (int)cvtpk(tp[r4 + 2][c], tp[r4 + 3][c]);
    *(int2*)(out + (size_t)(c0 + c) * R + r0 + r4) = v;
  }
}

// ---------------------------------------------------------------------------
// fc1: 256x256 tile, BK=32, splitK=4, 512 threads, 3-stage pipeline.
// Per iter t (98 tiles/split): AISSUE(t+2); vmcnt(10)+lgkm(0); barrier;
// BISSUE(t+2); MFMA(buf t); AWRITE(t+1).  Tail peels vmcnt 6 -> 0.
// Swizzle (64B rows): byte ^= ((row>>1)&3)<<4, both sides.
// ---------------------------------------------------------------------------
__global__ __launch_bounds__(512, 2) void gemm8p(
    const float* __restrict__ A, const u16* __restrict__ Bt,
    float* __restrict__ P) {
  const int K = 12544;                 // 4 splits x 98 tiles x BK=32
  __shared__ u16 lds[49152];           // 3 buf x (A 8192 + B 8192 elems) 96KB
  int tid = threadIdx.x;
  int w = tid >> 6, l = tid & 63, h = l >> 4, l15 = l & 15;
  int wm = w >> 2, wn = w & 3;

  int b = ((blockIdx.x & 7) << 5) | (blockIdx.x >> 3);   // XCD-chunked swizzle
  int bz = b >> 6, rest = b & 63;
  int bm = (rest & 15) * 256;
  int bn = (rest >> 4) * 256;
  size_t k0 = (size_t)bz * 3136;

  // A fp32 staging: thread -> row tid>>1 (0..255), cols (tid&1)*16 .. +15
  int arw = tid >> 1, acl = (tid & 1) * 16;
  const float* pA0 = A + (size_t)(bm + arw) * K + k0 + acl;
  int aswz = ((arw >> 1) & 3) << 4;                      // byte XOR
  int awq0 = ((arw * 64 + acl * 2)      ^ aswz) >> 1;    // elem offsets
  int awq1 = ((arw * 64 + acl * 2 + 16) ^ aswz) >> 1;

  // B staging: 2 gload16/thread, pre-swizzled global source, linear dest
  const u16* pBg0; const u16* pBg1;
  {
    int d0 = tid * 16, d1 = 8192 + tid * 16;             // byte in B region
    int r0 = d0 >> 6, r1 = d1 >> 6;
    int s0 = ((d0 & 63) ^ (((r0 >> 1) & 3) << 4)) >> 1;
    int s1 = ((d1 & 63) ^ (((r1 >> 1) & 3) << 4)) >> 1;
    pBg0 = Bt + (size_t)(bn + r0) * K + k0 + s0;
    pBg1 = Bt + (size_t)(bn + r1) * K + k0 + s1;
  }

  // frag-read swizzled k-offset (row base multiple of 16 -> depends on l15)
  int xk = (h * 8) ^ (((l15 >> 1) & 3) << 3);
  int rA = (wm * 64 + l15) * 32;
  int rB = (wn * 32 + l15) * 32;

  f32x4 acc[8][4];
#pragma unroll
  for (int i = 0; i < 8; i++)
#pragma unroll
    for (int j = 0; j < 4; j++) acc[i][j] = (f32x4){0.f, 0.f, 0.f, 0.f};

  float4 s0r[4], s1r[4];                // two A-reg sets (static indexing)

#define AISSUE(R, kk) { R[0] = *(const float4*)(pA0 + (kk));             \
    R[1] = *(const float4*)(pA0 + (kk) + 4);                             \
    R[2] = *(const float4*)(pA0 + (kk) + 8);                             \
    R[3] = *(const float4*)(pA0 + (kk) + 12); }
#define AWRITE(R, BUF) {                                                 \
    int4 v0, v1;                                                         \
    v0.x = (int)cvtpk(R[0].x, R[0].y); v0.y = (int)cvtpk(R[0].z, R[0].w);\
    v0.z = (int)cvtpk(R[1].x, R[1].y); v0.w = (int)cvtpk(R[1].z, R[1].w);\
    v1.x = (int)cvtpk(R[2].x, R[2].y); v1.y = (int)cvtpk(R[2].z, R[2].w);\
    v1.z = (int)cvtpk(R[3].x, R[3].y); v1.w = (int)cvtpk(R[3].z, R[3].w);\
    *(int4*)&lds[(BUF) + awq0] = v0;                                     \
    *(int4*)&lds[(BUF) + awq1] = v1; }
#define BISSUE(BUF, kk) {                                                \
    gload16(pBg0 + (kk), &lds[(BUF) + 8192 + tid * 8]);                  \
    gload16(pBg1 + (kk), &lds[(BUF) + 12288 + tid * 8]); }
#define SBAR __builtin_amdgcn_sched_barrier(0)
#define MFMA_PHASE(BUF) {                                                \
    const u16* LA = lds + (BUF); const u16* LB = LA + 8192;              \
    bf16x8 bl[2], bh[2], af[4];                                          \
    _Pragma("unroll") for (int j = 0; j < 2; j++) {                      \
      bl[j] = *(const bf16x8*)&LB[rB + j * 512 + xk];                    \
      bh[j] = *(const bf16x8*)&LB[4096 + rB + j * 512 + xk];             \
    }                                                                    \
    _Pragma("unroll") for (int i = 0; i < 4; i++)                        \
      af[i] = *(const bf16x8*)&LA[rA + i * 512 + xk];                    \
    __builtin_amdgcn_s_setprio(1);                                       \
    _Pragma("unroll") for (int i = 0; i < 4; i++)                        \
      _Pragma("unroll") for (int j = 0; j < 2; j++) {                    \
        acc[i][j]     = mfma16(af[i], bl[j], acc[i][j]);                 \
        acc[i][2 + j] = mfma16(af[i], bh[j], acc[i][2 + j]);             \
      }                                                                  \
    __builtin_amdgcn_s_setprio(0);                                       \
    SBAR;                                                                \
    _Pragma("unroll") for (int i = 0; i < 4; i++)                        \
      af[i] = *(const bf16x8*)&LA[4096 + rA + i * 512 + xk];             \
    __builtin_amdgcn_s_setprio(1);                                       \
    _Pragma("unroll") for (int i = 0; i < 4; i++)                        \
      _Pragma("unroll") for (int j = 0; j < 2; j++) {                    \
        acc[4 + i][j]     = mfma16(af[i], bl[j], acc[4 + i][j]);         \
        acc[4 + i][2 + j] = mfma16(af[i], bh[j], acc[4 + i][2 + j]);     \
      }                                                                  \
    __builtin_amdgcn_s_setprio(0); }
#define ITER(T, RW, RL) {                                                \
    AISSUE(RL, ((T) + 2) * 32);                                          \
    asm volatile("s_waitcnt vmcnt(10) lgkmcnt(0)" ::: "memory");         \
    __builtin_amdgcn_s_barrier();                                        \
    SBAR;                                                                \
    BISSUE(nx2, ((T) + 2) * 32);                                         \
    MFMA_PHASE(cub);                                                     \
    SBAR;                                                                \
    AWRITE(RW, nx1);                                                     \
    cub = nx1; nx1 = nx2; nx2 = (nx2 == 32768) ? 0 : nx2 + 16384; }

  // ---- prologue: tiles 0,1 ----
  AISSUE(s0r, 0);
  BISSUE(0, 0);
  AWRITE(s0r, 0);                       // compiler auto-waits A(0) regs
  AISSUE(s1r, 32);
  BISSUE(16384, 32);
  int cub = 0, nx1 = 16384, nx2 = 32768;
  // outstanding: B(0):2, A(1):4, B(1):2

  for (int tt = 0; tt < 48; tt++) {     // t = 0..95
    ITER(2 * tt,     s1r, s0r);         // write tile t+1 (s1r), load t+2->s0r
    ITER(2 * tt + 1, s0r, s1r);
  }
  // ---- t = 96: no issues; wait B(96) (outstanding A(97):4 + B(97):2) ----
  asm volatile("s_waitcnt vmcnt(6) lgkmcnt(0)" ::: "memory");
  __builtin_amdgcn_s_barrier();
  SBAR;
  MFMA_PHASE(cub);
  SBAR;
  AWRITE(s1r, nx1);                     // tile 97 (loaded at t=95 into s1r)
  cub = nx1;
  // ---- t = 97 ----
  asm volatile("s_waitcnt vmcnt(0) lgkmcnt(0)" ::: "memory");
  __builtin_amdgcn_s_barrier();
  SBAR;
  MFMA_PHASE(cub);
#undef AISSUE
#undef AWRITE
#undef BISSUE
#undef MFMA_PHASE
#undef ITER
#undef SBAR

  float* dst = P + (size_t)bz * 4096 * 1024;
#pragma unroll
  for (int qr = 0; qr < 2; qr++)
#pragma unroll
    for (int i = 0; i < 4; i++)
#pragma unroll
      for (int qc = 0; qc < 2; qc++)
#pragma unroll
        for (int j = 0; j < 2; j++) {
          int row0 = bm + qr * 128 + wm * 64 + i * 16 + h * 4;
          int col  = bn + qc * 128 + wn * 32 + j * 16 + l15;
          f32x4 v = acc[qr * 4 + i][qc * 2 + j];
#pragma unroll
          for (int r = 0; r < 4; r++)
            dst[(size_t)(row0 + r) * 1024 + col] = v[r];
        }
}

// ---------------------------------------------------------------------------
// fc_reduce (blocks [0,2048), bf16-only out) || pos_logw ([2048,6144)).
// ---------------------------------------------------------------------------
__global__ __launch_bounds__(256) void reduce_pos_kernel(
    const float* __restrict__ P, const float* __restrict__ bias,
    u16* __restrict__ xb,
    const float* __restrict__ bbox,
    const float* __restrict__ Wpos1, const float* __restrict__ Wpos2,
    const float* __restrict__ bpos1, const float* __restrict__ bpos2,
    u16* __restrict__ logw1, u16* __restrict__ logw2) {
  __shared__ u16 pool[18944];     // emb 64*88 | wp 32*88 | lw 2*16*328
  int tid = threadIdx.x;
  if (blockIdx.x < 2048) {        // ---- fc1 split-K reduce (bf16 out) ----
    const size_t MN = (size_t)4096 * 1024;
    size_t i = ((size_t)blockIdx.x * 256 + tid) * 4;
    size_t stride = (size_t)2048 * 256 * 4;
    for (; i < MN; i += stride) {
      float4 a = *(const float4*)(P + i);
      float4 b = *(const float4*)(P + MN + i);
      float4 c = *(const float4*)(P + 2 * MN + i);
      float4 d = *(const float4*)(P + 3 * MN + i);
      float4 bv = *(const float4*)(bias + (i & 1023));
      float4 r;
      r.x = a.x + b.x + c.x + d.x + bv.x;
      r.y = a.y + b.y + c.y + d.y + bv.y;
      r.z = a.z + b.z + c.z + d.z + bv.z;
      r.w = a.w + b.w + c.w + d.w + bv.w;
      int2 hv; hv.x = (int)cvtpk(r.x, r.y); hv.y = (int)cvtpk(r.z, r.w);
      *(int2*)(xb + i) = hv;
    }
    return;
  }
  // ---- pos_logw ----
  u16* emb_s = pool;              // [64][88]
  u16* wp_s  = pool + 5632;       // [32][88]
  u16* lw_s  = pool + 8448;       // [2*16][328]
  int n = blockIdx.x - 2048;
  int w = tid >> 6, l = tid & 63, h = l >> 4, l15 = l & 15;
  for (int idx = tid; idx < 1024; idx += 256) {   // stage Wpos^T both layers
    int e = idx >> 4, c = idx & 15;               // Wpos[e][c]
    wp_s[c * 88 + e]        = f2bf(Wpos1[idx]);
    wp_s[(16 + c) * 88 + e] = f2bf(Wpos2[idx]);
  }
  float4 bn = ((const float4*)bbox)[n];
  float bw_n = bn.z - bn.x + 1.f, bh_n = bn.w - bn.y + 1.f;
  float cx_n = 0.5f * (bn.x + bn.z), cy_n = 0.5f * (bn.y + bn.w);
  float bps0 = bpos1[l15], bps1 = bpos2[l15];
  int pr = tid >> 2, k = tid & 3;

  for (int m0 = 0; m0 < 320; m0 += 64) {
    int m = m0 + pr;
    float4 bm = ((const float4*)bbox)[m];
    float v;
    if (k == 0)      v = logf(fmaxf(fabsf((cx_n - 0.5f * (bm.x + bm.z)) / bw_n), 1e-3f));
    else if (k == 1) v = logf(fmaxf(fabsf((cy_n - 0.5f * (bm.y + bm.w)) / bh_n), 1e-3f));
    else if (k == 2) v = logf(bw_n / (bm.z - bm.x + 1.f));
    else             v = logf(bh_n / (bm.w - bm.y + 1.f));
    __syncthreads();                      // protect previous tile's frag reads
#pragma unroll
    for (int tt = 0; tt < 8; tt++) {
      float s, c; fsincos(v * C100D[tt], &s, &c);
      emb_s[pr * 88 + k * 16 + tt]     = f2bf(s);
      emb_s[pr * 88 + k * 16 + 8 + tt] = f2bf(c);
    }
    __syncthreads();
    f32x4 acc0 = {0.f, 0.f, 0.f, 0.f}, acc1 = {0.f, 0.f, 0.f, 0.f};
    bf16x8 a0 = *(const bf16x8*)&emb_s[(w * 16 + l15) * 88 + h * 8];
    bf16x8 a1 = *(const bf16x8*)&emb_s[(w * 16 + l15) * 88 + 32 + h * 8];
    bf16x8 b00 = *(const bf16x8*)&wp_s[l15 * 88 + h * 8];
    bf16x8 b01 = *(const bf16x8*)&wp_s[l15 * 88 + 32 + h * 8];
    bf16x8 b10 = *(const bf16x8*)&wp_s[(16 + l15) * 88 + h * 8];
    bf16x8 b11 = *(const bf16x8*)&wp_s[(16 + l15) * 88 + 32 + h * 8];
    acc0 = mfma16(a0, b00, acc0); acc0 = mfma16(a1, b01, acc0);
    acc1 = mfma16(a0, b10, acc1); acc1 = mfma16(a1, b11, acc1);
#pragma unroll
    for (int r = 0; r < 4; r++) {
      int mm = m0 + w * 16 + h * 4 + r;
      lw_s[l15 * 328 + mm]        = f2bf(logf(fmaxf(acc0[r] + bps0, 1e-6f)));
      lw_s[(16 + l15) * 328 + mm] = f2bf(logf(fmaxf(acc1[r] + bps1, 1e-6f)));
    }
  }
  __syncthreads();
  for (int i = tid; i < 1280; i += 256) {       // 2 layers * 16 g * 40 segs
    int layer = i / 640, rest = i - layer * 640;
    int gg = rest / 40, seg = rest - gg * 40;
    bf16x8 v = *(const bf16x8*)&lw_s[(layer * 16 + gg) * 328 + seg * 8];
    u16* dst = (layer ? logw2 : logw1) + ((size_t)gg * 4096 + n) * 320 + seg * 8;
    *(bf16x8*)dst = v;
  }
}

// ---------------------------------------------------------------------------
// gemmU: 128x128-tile BK=64 pipelined GEMM (64KB LDS -> 2 blocks/CU),
// up to 3 problems per grid.  C = A[MxK]*Bt[NxK]^T (+bias), bf16 out.
// ---------------------------------------------------------------------------
struct GDesc {
  const u16* A; const u16* Bt; const float* bias;
  u16* Cb;
  int M, N, K, ldc, nt;          // nt = #128-wide col tiles
};

__global__ __launch_bounds__(256, 2) void gemmU(GDesc g0, GDesc g1, GDesc g2,
                                                int c0, int c1) {
  __shared__ u16 lds[32768];     // 2 buf x (A 128x64 + B 128x64) bf16 = 64 KB
  GDesc g; int lb = blockIdx.x;
  if (lb < c0) { g = g0; lb = (lb & 7) * (c0 >> 3) + (lb >> 3); }  // XCD swz
  else if (lb < c1) { g = g1; lb -= c0; }
  else { g = g2; lb -= c1; }
  int bm = (lb / g.nt) * 128, bn = (lb % g.nt) * 128;
  int tid = threadIdx.x;
  int w = tid >> 6, l = tid & 63, h = l >> 4, l15 = l & 15;
  int wm = w >> 1, wn = w & 1;
  int K = g.K;

  int X = ((tid >> 3) & 7) << 4;
  int lbyte = (tid * 16) ^ X;
  int lr = lbyte >> 7, lc = (lbyte & 127) >> 1;
  const u16 *pa[4], *pb[4];
#pragma unroll
  for (int c = 0; c < 4; c++) {
    pa[c] = g.A  + (size_t)min(bm + c * 32 + lr, g.M - 1) * K + lc;
    pb[c] = g.Bt + (size_t)min(bn + c * 32 + lr, g.N - 1) * K + lc;
  }

  int swz = (l15 & 7) << 3;
  int xk0 = (h * 8) ^ swz;
  int xk1 = 32 ^ xk0;
  int rA = (wm * 64 + l15) * 64;
  int rB = (wn * 64 + l15) * 64;

  f32x4 acc[4][4];
#pragma unroll
  for (int i = 0; i < 4; i++)
#pragma unroll
    for (int j = 0; j < 4; j++) acc[i][j] = (f32x4){0.f, 0.f, 0.f, 0.f};

#define ISSUEU(W, kk)                                     \
  { gload16(pa[0] + (kk), (W) + tid * 8);                 \
    gload16(pa[1] + (kk), (W) + 2048 + tid * 8);          \
    gload16(pa[2] + (kk), (W) + 4096 + tid * 8);          \
    gload16(pa[3] + (kk), (W) + 6144 + tid * 8);          \
    gload16(pb[0] + (kk), (W) + 8192 + tid * 8);          \
    gload16(pb[1] + (kk), (W) + 10240 + tid * 8);         \
    gload16(pb[2] + (kk), (W) + 12288 + tid * 8);         \
    gload16(pb[3] + (kk), (W) + 14336 + tid * 8); }

  ISSUEU(lds, 0);
  int ktiles = K >> 6;
  for (int t = 0; t < ktiles; t++) {
    const u16* LA = lds + (t & 1) * 16384;
    const u16* LB = LA + 8192;
    u16* W = lds + ((t ^ 1) & 1) * 16384;
    if (t < ktiles - 1) {
      ISSUEU(W, (t + 1) * 64);
      asm volatile("s_waitcnt vmcnt(8)" ::: "memory");
    } else {
      asm volatile("s_waitcnt vmcnt(0)" ::: "memory");
    }
    __builtin_amdgcn_s_barrier();
    asm volatile("" ::: "memory");
    bf16x8 a[4][2], bfr[4][2];
#pragma unroll
    for (int i = 0; i < 4; i++) {
      a[i][0] = *(const bf16x8*)&LA[rA + i * 1024 + xk0];
      a[i][1] = *(const bf16x8*)&LA[rA + i * 1024 + xk1];
    }
#pragma unroll
    for (int j = 0; j < 4; j++) {
      bfr[j][0] = *(const bf16x8*)&LB[rB + j * 1024 + xk0];
      bfr[j][1] = *(const bf16x8*)&LB[rB + j * 1024 + xk1];
    }
    __builtin_amdgcn_s_setprio(1);
#pragma unroll
    for (int i = 0; i < 4; i++)
#pragma unroll
      for (int j = 0; j < 4; j++) {
        acc[i][j] = mfma16(a[i][0], bfr[j][0], acc[i][j]);
        acc[i][j] = mfma16(a[i][1], bfr[j][1], acc[i][j]);
      }
    __builtin_amdgcn_s_setprio(0);
    asm volatile("" ::: "memory");
    __builtin_amdgcn_s_barrier();
  }
#undef ISSUEU

#pragma unroll
  for (int i = 0; i < 4; i++) {
#pragma unroll
    for (int j = 0; j < 4; j++) {
      int col = bn + wn * 64 + j * 16 + l15;
      if (col >= g.ldc) continue;
      float bv = (g.bias != nullptr && col < g.N) ? g.bias[col] : 0.f;
      int row0 = bm + wm * 64 + i * 16 + h * 4;
#pragma unroll
      for (int r = 0; r < 4; r++) {
        int row = row0 + r;
        if (row >= g.M) continue;
        g.Cb[(size_t)row * g.ldc + col] = f2bf(acc[i][j][r] + bv);
      }
    }
  }
}

// ---------------------------------------------------------------------------
// fused attention per (64-row n-tile, head g).  Residual from bf16 xr.
// ---------------------------------------------------------------------------
template <bool LAST>
__global__ __launch_bounds__(256) void attn_kernel(
    const u16* __restrict__ qb, const u16* __restrict__ kb,
    const u16* __restrict__ kvt, const u16* __restrict__ logw,
    const u16* __restrict__ xr, const float* __restrict__ bo,
    float* __restrict__ outf, u16* __restrict__ outb) {
  __shared__ u16 ps[64 * 344];      // logw [64][328]; then P [64][344]
  int tid = threadIdx.x;
  int g = blockIdx.y, n0 = blockIdx.x * 64;
  int w = tid >> 6, l = tid & 63, h = l >> 4, l15 = l & 15;

  {                                 // stage logw tile (contiguous 40KB)
    const u16* src = logw + ((size_t)g * 4096 + n0) * 320;
    for (int i = tid; i < 64 * 40; i += 256) {
      int row = i / 40, seg = i - row * 40;
      *(bf16x8*)&ps[row * 328 + seg * 8] = *(const bf16x8*)(src + row * 320 + seg * 8);
    }
  }
  int nrow = n0 + w * 16 + l15;
  const u16* qp = qb + (size_t)nrow * 1024 + g * 64;
  bf16x8 aq0 = *(const bf16x8*)(qp + h * 8);
  bf16x8 aq1 = *(const bf16x8*)(qp + 32 + h * 8);

  f32x4 acc[19];
#pragma unroll
  for (int f = 0; f < 19; f++) acc[f] = (f32x4){0.f, 0.f, 0.f, 0.f};
  const u16* kp = kb + g * 64 + h * 8;
#pragma unroll
  for (int f = 0; f < 19; f++) {      // QK^T, K frags direct from global (L2)
    bf16x8 b0 = *(const bf16x8*)(kp + (size_t)(f * 16 + l15) * 1024);
    bf16x8 b1 = *(const bf16x8*)(kp + (size_t)(f * 16 + l15) * 1024 + 32);
    acc[f] = mfma16(aq0, b0, acc[f]);
    acc[f] = mfma16(aq1, b1, acc[f]);
  }
  __syncthreads();                    // logw staged

  int nbase = n0 + w * 16 + h * 4;
  int lrow = w * 16 + h * 4;
  float mx[4] = {-INFINITY, -INFINITY, -INFINITY, -INFINITY};
  float sm[4] = {0.f, 0.f, 0.f, 0.f};
#pragma unroll
  for (int f = 0; f < 19; f++) {
    int m = f * 16 + l15;
#pragma unroll
    for (int r = 0; r < 4; r++) {
      float lw = -INFINITY;
      if (m < 300) lw = bf2f(ps[(lrow + r) * 328 + m]);
      float lg = acc[f][r] * 0.125f + lw;
      acc[f][r] = lg;
      mx[r] = fmaxf(mx[r], lg);
    }
  }
#pragma unroll
  for (int d = 1; d < 16; d <<= 1)
#pragma unroll
    for (int r = 0; r < 4; r++) mx[r] = fmaxf(mx[r], __shfl_xor(mx[r], d));
#pragma unroll
  for (int f = 0; f < 19; f++)
#pragma unroll
    for (int r = 0; r < 4; r++) {
      float p = __expf(acc[f][r] - mx[r]);
      acc[f][r] = p; sm[r] += p;
    }
#pragma unroll
  for (int d = 1; d < 16; d <<= 1)
#pragma unroll
    for (int r = 0; r < 4; r++) sm[r] += __shfl_xor(sm[r], d);
  float inv[4];
#pragma unroll
  for (int r = 0; r < 4; r++) inv[r] = 1.f / sm[r];

  __syncthreads();                    // all waves done reading logw
#pragma unroll
  for (int f = 0; f < 19; f++)
#pragma unroll
    for (int r = 0; r < 4; r++)
      ps[(lrow + r) * 344 + f * 16 + l15] = f2bf(acc[f][r]);
#pragma unroll
  for (int r = 0; r < 4; r++)         // zero pad m 304..319
    ps[(lrow + r) * 344 + 304 + l15] = 0;

  f32x4 acc2[4];
#pragma unroll
  for (int fo = 0; fo < 4; fo++) acc2[fo] = (f32x4){0.f, 0.f, 0.f, 0.f};
  const u16* vp = kvt + (size_t)g * 64 * 320 + h * 8;
#pragma unroll
  for (int ks = 0; ks < 10; ks++) {   // PV: P rows are wave-local; KVt global
    bf16x8 ap = *(const bf16x8*)&ps[(w * 16 + l15) * 344 + ks * 32 + h * 8];
#pragma unroll
    for (int fo = 0; fo < 4; fo++) {
      bf16x8 bv = *(const bf16x8*)(vp + (size_t)(fo * 16 + l15) * 320 + ks * 32);
      acc2[fo] = mfma16(ap, bv, acc2[fo]);
    }
  }
#pragma unroll
  for (int fo = 0; fo < 4; fo++) {
    int col = g * 64 + fo * 16 + l15;
    float bov = bo[col];
#pragma unroll
    for (int r = 0; r < 4; r++) {
      int row = nbase + r;
      size_t off = (size_t)row * 1024 + col;
      float v = bf2f(xr[off]) + acc2[fo][r] * inv[r] + bov;
      v = fmaxf(v, 0.f);
      if (LAST) outf[off] = v;
      else      outb[off] = f2bf(v);
    }
  }
}

// ---------------------------------------------------------------------------
extern "C" void kernel_launch(void* const* d_in, const int* in_sizes, int n_in,
                              void* d_out, int out_size, void* d_ws, size_t ws_size,
                              hipStream_t stream) {
  (void)in_sizes; (void)n_in; (void)out_size; (void)ws_size;
  const float* roi   = (const float*)d_in[0];
  const float* bbox  = (const float*)d_in[1];
  const float* Wfc1  = (const float*)d_in[2];
  const float* bfc1  = (const float*)d_in[3];
  const float* Wfc2  = (const float*)d_in[4];
  const float* bfc2  = (const float*)d_in[5];
  const float* Wpos1 = (const float*)d_in[6];
  const float* bpos1 = (const float*)d_in[7];
  const float* Wq1   = (const float*)d_in[8];
  const float* bq1   = (const float*)d_in[9];
  const float* Wk1   = (const float*)d_in[10];
  const float* bk1   = (const float*)d_in[11];
  const float* Wo1   = (const float*)d_in[12];
  const float* bo1   = (const float*)d_in[13];
  const float* Wpos2 = (const float*)d_in[14];
  const float* bpos2 = (const float*)d_in[15];
  const float* Wq2   = (const float*)d_in[16];
  const float* bq2   = (const float*)d_in[17];
  const float* Wk2   = (const float*)d_in[18];
  const float* bk2   = (const float*)d_in[19];
  const float* Wo2   = (const float*)d_in[20];
  const float* bo2   = (const float*)d_in[21];

  char* ws = (char*)d_ws;                       // ---- workspace arena ----
  u16*  Wfc1_t = (u16*)(ws + 102760448);        //  25,690,112
  u16*  Wfc2_t = (u16*)(ws + 128450560);        //   2,097,152 each
  u16*  Wq1_t  = (u16*)(ws + 130547712);
  u16*  Wk1_t  = (u16*)(ws + 132644864);
  u16*  Wq2_t  = (u16*)(ws + 134742016);
  u16*  Wk2_t  = (u16*)(ws + 136839168);
  u16*  Wo1_b  = (u16*)(ws + 138936320);
  u16*  Wo2_b  = (u16*)(ws + 141033472);
  float* Pp    = (float*)(ws + 143134720);      //  67,108,864 (splitK=4)
  u16*  xb_f   = (u16*)(ws + 243798016);        //   8,388,608 (fc out, bf16)
  u16*  xb_a   = (u16*)(ws + 252186624);        //   8,388,608 (attn out, bf16)
  u16*  q_b    = (u16*)(ws + 260575232);        //   8,388,608
  u16*  k_b    = (u16*)(ws + 268963840);        //     614,400
  u16*  kvt_b  = (u16*)(ws + 269578240);        //     655,360
  u16*  logw1  = (u16*)(ws + 270233600);        //  41,943,040
  u16*  logw2  = (u16*)(ws + 312176640);        //  41,943,040 (end 354,119,680)

  {                                             // 1. prep (weight converts)
    PrepArgs p;
    p.Wo1 = Wo1;   p.Wo1_b = Wo1_b;
    p.Wo2 = Wo2;   p.Wo2_b = Wo2_b;
    p.Wfc1 = Wfc1; p.Wfc1_t = Wfc1_t;
    p.wsrc[0] = Wfc2; p.wdst[0] = Wfc2_t;
    p.wsrc[1] = Wq1;  p.wdst[1] = Wq1_t;
    p.wsrc[2] = Wk1;  p.wdst[2] = Wk1_t;
    p.wsrc[3] = Wq2;  p.wdst[3] = Wq2_t;
    p.wsrc[4] = Wk2;  p.wdst[4] = Wk2_t;
    prep_kernel<<<18688, 256, 0, stream>>>(p);
  }
  // 2. fc1 splitK=4, 3-stage pipeline (reads fp32 roi directly)
  gemm8p<<<256, 512, 0, stream>>>(roi, Wfc1_t, Pp);
  // 3. reduce (bf16 out) || pos tables
  reduce_pos_kernel<<<6144, 256, 0, stream>>>(Pp, bfc1, xb_f, bbox,
                                              Wpos1, Wpos2, bpos1, bpos2,
                                              logw1, logw2);
  // ---- layer 1 ----
  {
    GDesc q  = {xb_f,  Wq1_t, bq1, q_b,   4096, 1024, 1024, 1024, 8};
    GDesc kk = {xb_f,  Wk1_t, bk1, k_b,    300, 1024, 1024, 1024, 8};
    GDesc kv = {Wo1_b, xb_f,  nullptr, kvt_b, 1024, 300, 1024, 320, 3};
    gemmU<<<304, 256, 0, stream>>>(q, kk, kv, 256, 280);
  }
  attn_kernel<false><<<dim3(64, 16), 256, 0, stream>>>(q_b, k_b, kvt_b, logw1, xb_f, bo1, nullptr, xb_a);

  // ---- layer 2 ----
  {
    GDesc fc = {xb_a, Wfc2_t, bfc2, xb_f, 4096, 1024, 1024, 1024, 8};
    gemmU<<<256, 256, 0, stream>>>(fc, fc, fc, 256, 256);
  }
  {
    GDesc q  = {xb_f,  Wq2_t, bq2, q_b,   4096, 1024, 1024, 1024, 8};
    GDesc kk = {xb_f,  Wk2_t, bk2, k_b,    300, 1024, 1024, 1024, 8};
    GDesc kv = {Wo2_b, xb_f,  nullptr, kvt_b, 1024, 300, 1024, 320, 3};
    gemmU<<<304, 256, 0, stream>>>(q, kk, kv, 256, 280);
  }
  attn_kernel<true><<<dim3(64, 16), 256, 0, stream>>>(q_b, k_b, kvt_b, logw2, xb_f, bo2, (float*)d_out, nullptr);
}

// Round 15
// 377.140 us; speedup vs baseline: 1.0537x; 1.0537x over previous
//
#include <hip/hip_runtime.h>

// ============================================================================
// FastRCNN Relation FC Head, MI355X round 15.
// Revert to round-13 structure (best, 383.3us: r11 gemm8p frozen) + prep
// split: prep now transposes ONLY Wfc1 (the single gemm8p dependency);
// the other 7 weight tensors (Wo converts + 5x 1024^2 transposes) move into
// the reduce_pos launch where they hide under pos's VALU-bound slack.
// Workspace: 354 MB.
// ============================================================================

using bf16x8 = __attribute__((ext_vector_type(8))) short;
using f32x4  = __attribute__((ext_vector_type(4))) float;
typedef unsigned short u16;
typedef unsigned int   u32;

#define DEV __device__ __forceinline__

DEV u32 cvtpk(float lo, float hi) {          // 2x fp32 -> packed bf16 (1 instr)
  u32 r;
  asm("v_cvt_pk_bf16_f32 %0, %1, %2" : "=v"(r) : "v"(lo), "v"(hi));
  return r;
}
DEV u16 f2bf(float f) { return (u16)cvtpk(f, f); }
DEV float bf2f(u16 h) { return __uint_as_float(((u32)h) << 16); }

DEV f32x4 mfma16(bf16x8 a, bf16x8 b, f32x4 c) {
  return __builtin_amdgcn_mfma_f32_16x16x32_bf16(a, b, c, 0, 0, 0);
}
DEV void gload16(const u16* g, u16* l) {
  __builtin_amdgcn_global_load_lds((const __attribute__((address_space(1))) void*)g,
                                   (__attribute__((address_space(3))) void*)l, 16, 0, 0);
}

DEV void fsincos(float x, float* s, float* c) {
  float r = x * 0.15915494309189535f;   // revolutions, exact-identity reduction
  r -= rintf(r);
  float a = r * 6.283185307179586f;
  *s = __sinf(a); *c = __cosf(a);
}

__constant__ float C100D[8] = {100.f, 42.16965034285822f, 17.78279410038923f,
                               7.498942093324559f, 3.1622776601683795f,
                               1.333521432163324f, 0.5623413251903491f,
                               0.23713737056616552f};

// ---------------------------------------------------------------------------
// prep: Wfc1 transpose+convert ONLY (12544 blocks of 32x32 tiles).
// ---------------------------------------------------------------------------
__global__ __launch_bounds__(256) void prep_kernel(const float* __restrict__ Wfc1,
                                                   u16* __restrict__ Wfc1_t) {
  __shared__ float tp[32][36];
  int b = blockIdx.x, tid = threadIdx.x;
  const int R = 12544, C = 1024;
  int r0 = (b >> 5) * 32, c0 = (b & 31) * 32;
  {                                             // 32x32 vectorized transpose
    int r = tid >> 3, c4 = (tid & 7) * 4;
    float4 v = *(const float4*)(Wfc1 + (size_t)(r0 + r) * C + c0 + c4);
    *(float4*)&tp[r][c4] = v;
  }
  __syncthreads();
  {
    int c = tid >> 3, r4 = (tid & 7) * 4;
    int2 v;
    v.x = (int)cvtpk(tp[r4 + 0][c], tp[r4 + 1][c]);
    v.y = (int)cvtpk(tp[r4 + 2][c], tp[r4 + 3][c]);
    *(int2*)(Wfc1_t + (size_t)(c0 + c) * R + r0 + r4) = v;
  }
}

// ---------------------------------------------------------------------------
// fc1: 256x256-tile, BK=64, 512 threads, splitK=4 (r11 schedule, frozen).
// ---------------------------------------------------------------------------
__global__ __launch_bounds__(512, 2) void gemm8p(
    const float* __restrict__ A, const u16* __restrict__ Bt,
    float* __restrict__ P) {
  const int K = 12544;                 // 4 splits x 49 tiles x BK=64
  __shared__ u16 lds[65536];           // 2 buf x (A 32KB + B 32KB) = 128 KB
  int tid = threadIdx.x;
  int w = tid >> 6, l = tid & 63, h = l >> 4, l15 = l & 15;
  int wm = w >> 2, wn = w & 3;

  int b = ((blockIdx.x & 7) << 5) | (blockIdx.x >> 3);   // XCD-chunked swizzle
  int bz = b >> 6, rest = b & 63;
  int bm = (rest & 15) * 256;
  int bn = (rest >> 4) * 256;
  size_t k0 = (size_t)bz * 3136;

  int arow = tid >> 3;                      // A staging: row within chunk
  int c0 = (tid & 7) * 8;                   // col (elems)
  const float* pA0 = A + (size_t)(bm + arow) * K + k0 + c0;
  const size_t aseg = (size_t)64 * K;
  int awe = ((arow * 128 + c0 * 2) ^ ((arow & 7) << 4)) >> 1;          // elems

  int X = ((tid >> 3) & 7) << 4;
  int lb2 = (tid * 16) ^ X;
  int lr = lb2 >> 7, lc = (lb2 & 127) >> 1;
  const u16* pB = Bt + (size_t)(bn + lr) * K + k0 + lc;
  const size_t o64 = (size_t)64 * K, o128 = (size_t)128 * K, o192 = (size_t)192 * K;

  int swz = (l15 & 7) << 3;
  int xk0 = (h * 8) ^ swz;
  int xk1 = 32 ^ xk0;
  int rA = (wm * 64 + l15) * 64;
  int rB = (wn * 32 + l15) * 64;

  f32x4 acc[8][4];
#pragma unroll
  for (int i = 0; i < 8; i++)
#pragma unroll
    for (int j = 0; j < 4; j++) acc[i][j] = (f32x4){0.f, 0.f, 0.f, 0.f};

  float4 a0[4], a1[4];
  bf16x8 af[4][2], bl[2][2], bh[2][2];

#define AISSUE(kk) { _Pragma("unroll") for (int s = 0; s < 4; s++) {     \
    a0[s] = *(const float4*)(pA0 + s * aseg + (kk));                     \
    a1[s] = *(const float4*)(pA0 + s * aseg + (kk) + 4); } }
#define BISSUE_LO(WB, kk) {                                              \
    gload16(pB + (kk),        (WB) + tid * 8);                           \
    gload16(pB + o64 + (kk),  (WB) + 4096 + tid * 8); }
#define BISSUE_HI(WB, kk) {                                              \
    gload16(pB + o128 + (kk), (WB) + 8192 + tid * 8);                    \
    gload16(pB + o192 + (kk), (WB) + 12288 + tid * 8); }
#define AWRITE(WA) { _Pragma("unroll") for (int s = 0; s < 4; s++) {     \
    int4 v;                                                              \
    v.x = (int)cvtpk(a0[s].x, a0[s].y);                                  \
    v.y = (int)cvtpk(a0[s].z, a0[s].w);                                  \
    v.z = (int)cvtpk(a1[s].x, a1[s].y);                                  \
    v.w = (int)cvtpk(a1[s].z, a1[s].w);                                  \
    *(int4*)&(WA)[awe + s * 4096] = v; } }
#define READ_AF(BASE)                                                    \
  _Pragma("unroll") for (int i = 0; i < 4; i++) {                        \
    af[i][0] = *(const bf16x8*)&LA[(BASE) + rA + i * 1024 + xk0];        \
    af[i][1] = *(const bf16x8*)&LA[(BASE) + rA + i * 1024 + xk1];        \
  }
#define READ_BL {                                                        \
  _Pragma("unroll") for (int j = 0; j < 2; j++) {                        \
    bl[j][0] = *(const bf16x8*)&LB[rB + j * 1024 + xk0];                 \
    bl[j][1] = *(const bf16x8*)&LB[rB + j * 1024 + xk1]; } }
#define READ_BH {                                                        \
  _Pragma("unroll") for (int j = 0; j < 2; j++) {                        \
    bh[j][0] = *(const bf16x8*)&LB[8192 + rB + j * 1024 + xk0];          \
    bh[j][1] = *(const bf16x8*)&LB[8192 + rB + j * 1024 + xk1]; } }
#define Q_MFMA(QR, QC, BF)                                               \
  __builtin_amdgcn_s_setprio(1);                                         \
  _Pragma("unroll") for (int i = 0; i < 4; i++)                          \
    _Pragma("unroll") for (int j = 0; j < 2; j++) {                      \
      acc[(QR)*4+i][(QC)*2+j] = mfma16(af[i][0], BF[j][0], acc[(QR)*4+i][(QC)*2+j]); \
      acc[(QR)*4+i][(QC)*2+j] = mfma16(af[i][1], BF[j][1], acc[(QR)*4+i][(QC)*2+j]); \
    }                                                                    \
  __builtin_amdgcn_s_setprio(0);
#define SBAR __builtin_amdgcn_sched_barrier(0)

  AISSUE(0);
  BISSUE_LO(lds + 16384, 0);
  BISSUE_HI(lds + 16384, 0);
  AWRITE(lds);
  asm volatile("s_waitcnt vmcnt(0) lgkmcnt(0)" ::: "memory");
  __builtin_amdgcn_s_barrier();

  for (int t = 0; t < 48; t++) {
    const u16* LA = lds + (t & 1) * 32768;
    const u16* LB = LA + 16384;
    u16* WA = lds + ((t + 1) & 1) * 32768;
    u16* WB = WA + 16384;
    int ktn = (t + 1) * 64;
    AISSUE(ktn);
    asm volatile("s_waitcnt vmcnt(10) lgkmcnt(0)" ::: "memory");
    __builtin_amdgcn_s_barrier();
    SBAR;
    READ_AF(0);
    READ_BL;
    Q_MFMA(0, 0, bl);
    SBAR;
    BISSUE_LO(WB, ktn);
    asm volatile("s_waitcnt vmcnt(10)" ::: "memory");
    __builtin_amdgcn_s_barrier();
    SBAR;
    READ_BH;
    Q_MFMA(0, 1, bh);
    SBAR;
    BISSUE_HI(WB, ktn);
    READ_AF(8192);
    Q_MFMA(1, 1, bh);
    SBAR;
    Q_MFMA(1, 0, bl);
    SBAR;
    AWRITE(WA);
  }
  {  // tail tile t=48 (buf0): counted drain 2 -> 0
    const u16* LA = lds;
    const u16* LB = lds + 16384;
    asm volatile("s_waitcnt vmcnt(2) lgkmcnt(0)" ::: "memory");
    __builtin_amdgcn_s_barrier();
    SBAR;
    READ_AF(0);
    READ_BL;
    Q_MFMA(0, 0, bl);
    SBAR;
    asm volatile("s_waitcnt vmcnt(0)" ::: "memory");
    __builtin_amdgcn_s_barrier();
    SBAR;
    READ_BH;
    Q_MFMA(0, 1, bh);
    SBAR;
    READ_AF(8192);
    Q_MFMA(1, 1, bh);
    Q_MFMA(1, 0, bl);
  }
#undef AISSUE
#undef BISSUE_LO
#undef BISSUE_HI
#undef AWRITE
#undef READ_AF
#undef READ_BL
#undef READ_BH
#undef Q_MFMA
#undef SBAR

  float* dst = P + (size_t)bz * 4096 * 1024;
#pragma unroll
  for (int qr = 0; qr < 2; qr++)
#pragma unroll
    for (int i = 0; i < 4; i++)
#pragma unroll
      for (int qc = 0; qc < 2; qc++)
#pragma unroll
        for (int j = 0; j < 2; j++) {
          int row0 = bm + qr * 128 + wm * 64 + i * 16 + h * 4;
          int col  = bn + qc * 128 + wn * 32 + j * 16 + l15;
          f32x4 v = acc[qr * 4 + i][qc * 2 + j];
#pragma unroll
          for (int r = 0; r < 4; r++)
            dst[(size_t)(row0 + r) * 1024 + col] = v[r];
        }
}

// ---------------------------------------------------------------------------
// reduce || pos || small-weight prep, one launch:
//  [0,2048)       fc1 split-K reduce (bf16 out)
//  [2048,6144)    pos_logw (one block per n)
//  [6144,7168)    Wo1/Wo2 fp32->bf16 converts
//  [7168,12288)   5x 1024x1024 transpose+convert (Wfc2,Wq1,Wk1,Wq2,Wk2)
// ---------------------------------------------------------------------------
struct RPArgs {
  const float* P; const float* bias; u16* xb;
  const float* bbox;
  const float* Wpos1; const float* Wpos2;
  const float* bpos1; const float* bpos2;
  u16* logw1; u16* logw2;
  const float* Wo1; u16* Wo1_b;
  const float* Wo2; u16* Wo2_b;
  const float* wsrc[5]; u16* wdst[5];
};

__global__ __launch_bounds__(256) void reduce_pos_kernel(RPArgs p) {
  __shared__ u16 pool[18944];     // emb 64*88 | wp 32*88 | lw 2*16*328
  int tid = threadIdx.x;
  int b = blockIdx.x;
  if (b < 2048) {                 // ---- fc1 split-K reduce (bf16 out) ----
    const size_t MN = (size_t)4096 * 1024;
    size_t i = ((size_t)b * 256 + tid) * 4;
    size_t stride = (size_t)2048 * 256 * 4;
    for (; i < MN; i += stride) {
      float4 a = *(const float4*)(p.P + i);
      float4 b2 = *(const float4*)(p.P + MN + i);
      float4 c = *(const float4*)(p.P + 2 * MN + i);
      float4 d = *(const float4*)(p.P + 3 * MN + i);
      float4 bv = *(const float4*)(p.bias + (i & 1023));
      float4 r;
      r.x = a.x + b2.x + c.x + d.x + bv.x;
      r.y = a.y + b2.y + c.y + d.y + bv.y;
      r.z = a.z + b2.z + c.z + d.z + bv.z;
      r.w = a.w + b2.w + c.w + d.w + bv.w;
      int2 hv; hv.x = (int)cvtpk(r.x, r.y); hv.y = (int)cvtpk(r.z, r.w);
      *(int2*)(p.xb + i) = hv;
    }
    return;
  }
  if (b < 6144) {                 // ---- pos_logw ----
    u16* emb_s = pool;            // [64][88]
    u16* wp_s  = pool + 5632;     // [32][88]
    u16* lw_s  = pool + 8448;     // [2*16][328]
    int n = b - 2048;
    int w = tid >> 6, l = tid & 63, h = l >> 4, l15 = l & 15;
    for (int idx = tid; idx < 1024; idx += 256) {   // stage Wpos^T both layers
      int e = idx >> 4, c = idx & 15;               // Wpos[e][c]
      wp_s[c * 88 + e]        = f2bf(p.Wpos1[idx]);
      wp_s[(16 + c) * 88 + e] = f2bf(p.Wpos2[idx]);
    }
    float4 bn = ((const float4*)p.bbox)[n];
    float bw_n = bn.z - bn.x + 1.f, bh_n = bn.w - bn.y + 1.f;
    float cx_n = 0.5f * (bn.x + bn.z), cy_n = 0.5f * (bn.y + bn.w);
    float bps0 = p.bpos1[l15], bps1 = p.bpos2[l15];
    int pr = tid >> 2, k = tid & 3;

    for (int m0 = 0; m0 < 320; m0 += 64) {
      int m = m0 + pr;
      float4 bm = ((const float4*)p.bbox)[m];
      float v;
      if (k == 0)      v = logf(fmaxf(fabsf((cx_n - 0.5f * (bm.x + bm.z)) / bw_n), 1e-3f));
      else if (k == 1) v = logf(fmaxf(fabsf((cy_n - 0.5f * (bm.y + bm.w)) / bh_n), 1e-3f));
      else if (k == 2) v = logf(bw_n / (bm.z - bm.x + 1.f));
      else             v = logf(bh_n / (bm.w - bm.y + 1.f));
      __syncthreads();                  // protect previous tile's frag reads
#pragma unroll
      for (int tt = 0; tt < 8; tt++) {
        float s, c; fsincos(v * C100D[tt], &s, &c);
        emb_s[pr * 88 + k * 16 + tt]     = f2bf(s);
        emb_s[pr * 88 + k * 16 + 8 + tt] = f2bf(c);
      }
      __syncthreads();
      f32x4 acc0 = {0.f, 0.f, 0.f, 0.f}, acc1 = {0.f, 0.f, 0.f, 0.f};
      bf16x8 a0 = *(const bf16x8*)&emb_s[(w * 16 + l15) * 88 + h * 8];
      bf16x8 a1 = *(const bf16x8*)&emb_s[(w * 16 + l15) * 88 + 32 + h * 8];
      bf16x8 b00 = *(const bf16x8*)&wp_s[l15 * 88 + h * 8];
      bf16x8 b01 = *(const bf16x8*)&wp_s[l15 * 88 + 32 + h * 8];
      bf16x8 b10 = *(const bf16x8*)&wp_s[(16 + l15) * 88 + h * 8];
      bf16x8 b11 = *(const bf16x8*)&wp_s[(16 + l15) * 88 + 32 + h * 8];
      acc0 = mfma16(a0, b00, acc0); acc0 = mfma16(a1, b01, acc0);
      acc1 = mfma16(a0, b10, acc1); acc1 = mfma16(a1, b11, acc1);
#pragma unroll
      for (int r = 0; r < 4; r++) {
        int mm = m0 + w * 16 + h * 4 + r;
        lw_s[l15 * 328 + mm]        = f2bf(logf(fmaxf(acc0[r] + bps0, 1e-6f)));
        lw_s[(16 + l15) * 328 + mm] = f2bf(logf(fmaxf(acc1[r] + bps1, 1e-6f)));
      }
    }
    __syncthreads();
    for (int i = tid; i < 1280; i += 256) {     // 2 layers * 16 g * 40 segs
      int layer = i / 640, rest = i - layer * 640;
      int gg = rest / 40, seg = rest - gg * 40;
      bf16x8 v = *(const bf16x8*)&lw_s[(layer * 16 + gg) * 328 + seg * 8];
      u16* dst = (layer ? p.logw2 : p.logw1) + ((size_t)gg * 4096 + n) * 320 + seg * 8;
      *(bf16x8*)dst = v;
    }
    return;
  }
  if (b < 7168) {                 // ---- Wo1/Wo2 converts ----
    int b2 = b - 6144;
    const float* src = (b2 < 512) ? p.Wo1 : p.Wo2;
    u16* dst = (b2 < 512) ? p.Wo1_b : p.Wo2_b;
    size_t i = ((size_t)(b2 & 511) * 256 + tid) * 8;
    float4 a = *(const float4*)(src + i);
    float4 c = *(const float4*)(src + i + 4);
    int4 v;
    v.x = (int)cvtpk(a.x, a.y); v.y = (int)cvtpk(a.z, a.w);
    v.z = (int)cvtpk(c.x, c.y); v.w = (int)cvtpk(c.z, c.w);
    *(int4*)(dst + i) = v;
    return;
  }
  {                               // ---- 5x 1024^2 transpose+convert ----
    float (*tp)[36] = (float(*)[36])pool;
    int idx = b - 7168;
    int z = idx >> 10, rest = idx & 1023;
    const float* in = p.wsrc[z]; u16* out = p.wdst[z];
    int r0 = (rest >> 5) * 32, c0 = (rest & 31) * 32;
    {
      int r = tid >> 3, c4 = (tid & 7) * 4;
      float4 v = *(const float4*)(in + (size_t)(r0 + r) * 1024 + c0 + c4);
      *(float4*)&tp[r][c4] = v;
    }
    __syncthreads();
    {
      int c = tid >> 3, r4 = (tid & 7) * 4;
      int2 v;
      v.x = (int)cvtpk(tp[r4 + 0][c], tp[r4 + 1][c]);
      v.y = (int)cvtpk(tp[r4 + 2][c], tp[r4 + 3][c]);
      *(int2*)(out + (size_t)(c0 + c) * 1024 + r0 + r4) = v;
    }
  }
}

// ---------------------------------------------------------------------------
// gemmU: 128x128-tile BK=64 pipelined GEMM (64KB LDS -> 2 blocks/CU),
// up to 3 problems per grid.  C = A[MxK]*Bt[NxK]^T (+bias), bf16 out.
// ---------------------------------------------------------------------------
struct GDesc {
  const u16* A; const u16* Bt; const float* bias;
  u16* Cb;
  int M, N, K, ldc, nt;          // nt = #128-wide col tiles
};

__global__ __launch_bounds__(256, 2) void gemmU(GDesc g0, GDesc g1, GDesc g2,
                                                int c0, int c1) {
  __shared__ u16 lds[32768];     // 2 buf x (A 128x64 + B 128x64) bf16 = 64 KB
  GDesc g; int lb = blockIdx.x;
  if (lb < c0) { g = g0; lb = (lb & 7) * (c0 >> 3) + (lb >> 3); }  // XCD swz
  else if (lb < c1) { g = g1; lb -= c0; }
  else { g = g2; lb -= c1; }
  int bm = (lb / g.nt) * 128, bn = (lb % g.nt) * 128;
  int tid = threadIdx.x;
  int w = tid >> 6, l = tid & 63, h = l >> 4, l15 = l & 15;
  int wm = w >> 1, wn = w & 1;
  int K = g.K;

  int X = ((tid >> 3) & 7) << 4;
  int lbyte = (tid * 16) ^ X;
  int lr = lbyte >> 7, lc = (lbyte & 127) >> 1;
  const u16 *pa[4], *pb[4];
#pragma unroll
  for (int c = 0; c < 4; c++) {
    pa[c] = g.A  + (size_t)min(bm + c * 32 + lr, g.M - 1) * K + lc;
    pb[c] = g.Bt + (size_t)min(bn + c * 32 + lr, g.N - 1) * K + lc;
  }

  int swz = (l15 & 7) << 3;
  int xk0 = (h * 8) ^ swz;
  int xk1 = 32 ^ xk0;
  int rA = (wm * 64 + l15) * 64;
  int rB = (wn * 64 + l15) * 64;

  f32x4 acc[4][4];
#pragma unroll
  for (int i = 0; i < 4; i++)
#pragma unroll
    for (int j = 0; j < 4; j++) acc[i][j] = (f32x4){0.f, 0.f, 0.f, 0.f};

#define ISSUEU(W, kk)                                     \
  { gload16(pa[0] + (kk), (W) + tid * 8);                 \
    gload16(pa[1] + (kk), (W) + 2048 + tid * 8);          \
    gload16(pa[2] + (kk), (W) + 4096 + tid * 8);          \
    gload16(pa[3] + (kk), (W) + 6144 + tid * 8);          \
    gload16(pb[0] + (kk), (W) + 8192 + tid * 8);          \
    gload16(pb[1] + (kk), (W) + 10240 + tid * 8);         \
    gload16(pb[2] + (kk), (W) + 12288 + tid * 8);         \
    gload16(pb[3] + (kk), (W) + 14336 + tid * 8); }

  ISSUEU(lds, 0);
  int ktiles = K >> 6;
  for (int t = 0; t < ktiles; t++) {
    const u16* LA = lds + (t & 1) * 16384;
    const u16* LB = LA + 8192;
    u16* W = lds + ((t ^ 1) & 1) * 16384;
    if (t < ktiles - 1) {
      ISSUEU(W, (t + 1) * 64);
      asm volatile("s_waitcnt vmcnt(8)" ::: "memory");
    } else {
      asm volatile("s_waitcnt vmcnt(0)" ::: "memory");
    }
    __builtin_amdgcn_s_barrier();
    asm volatile("" ::: "memory");
    bf16x8 a[4][2], bfr[4][2];
#pragma unroll
    for (int i = 0; i < 4; i++) {
      a[i][0] = *(const bf16x8*)&LA[rA + i * 1024 + xk0];
      a[i][1] = *(const bf16x8*)&LA[rA + i * 1024 + xk1];
    }
#pragma unroll
    for (int j = 0; j < 4; j++) {
      bfr[j][0] = *(const bf16x8*)&LB[rB + j * 1024 + xk0];
      bfr[j][1] = *(const bf16x8*)&LB[rB + j * 1024 + xk1];
    }
    __builtin_amdgcn_s_setprio(1);
#pragma unroll
    for (int i = 0; i < 4; i++)
#pragma unroll
      for (int j = 0; j < 4; j++) {
        acc[i][j] = mfma16(a[i][0], bfr[j][0], acc[i][j]);
        acc[i][j] = mfma16(a[i][1], bfr[j][1], acc[i][j]);
      }
    __builtin_amdgcn_s_setprio(0);
    asm volatile("" ::: "memory");
    __builtin_amdgcn_s_barrier();
  }
#undef ISSUEU

#pragma unroll
  for (int i = 0; i < 4; i++) {
#pragma unroll
    for (int j = 0; j < 4; j++) {
      int col = bn + wn * 64 + j * 16 + l15;
      if (col >= g.ldc) continue;
      float bv = (g.bias != nullptr && col < g.N) ? g.bias[col] : 0.f;
      int row0 = bm + wm * 64 + i * 16 + h * 4;
#pragma unroll
      for (int r = 0; r < 4; r++) {
        int row = row0 + r;
        if (row >= g.M) continue;
        g.Cb[(size_t)row * g.ldc + col] = f2bf(acc[i][j][r] + bv);
      }
    }
  }
}

// ---------------------------------------------------------------------------
// fused attention per (64-row n-tile, head g).  Residual from bf16 xr.
// ---------------------------------------------------------------------------
template <bool LAST>
__global__ __launch_bounds__(256) void attn_kernel(
    const u16* __restrict__ qb, const u16* __restrict__ kb,
    const u16* __restrict__ kvt, const u16* __restrict__ logw,
    const u16* __restrict__ xr, const float* __restrict__ bo,
    float* __restrict__ outf, u16* __restrict__ outb) {
  __shared__ u16 ps[64 * 344];      // logw [64][328]; then P [64][344]
  int tid = threadIdx.x;
  int g = blockIdx.y, n0 = blockIdx.x * 64;
  int w = tid >> 6, l = tid & 63, h = l >> 4, l15 = l & 15;

  {                                 // stage logw tile (contiguous 40KB)
    const u16* src = logw + ((size_t)g * 4096 + n0) * 320;
    for (int i = tid; i < 64 * 40; i += 256) {
      int row = i / 40, seg = i - row * 40;
      *(bf16x8*)&ps[row * 328 + seg * 8] = *(const bf16x8*)(src + row * 320 + seg * 8);
    }
  }
  int nrow = n0 + w * 16 + l15;
  const u16* qp = qb + (size_t)nrow * 1024 + g * 64;
  bf16x8 aq0 = *(const bf16x8*)(qp + h * 8);
  bf16x8 aq1 = *(const bf16x8*)(qp + 32 + h * 8);

  f32x4 acc[19];
#pragma unroll
  for (int f = 0; f < 19; f++) acc[f] = (f32x4){0.f, 0.f, 0.f, 0.f};
  const u16* kp = kb + g * 64 + h * 8;
#pragma unroll
  for (int f = 0; f < 19; f++) {      // QK^T, K frags direct from global (L2)
    bf16x8 b0 = *(const bf16x8*)(kp + (size_t)(f * 16 + l15) * 1024);
    bf16x8 b1 = *(const bf16x8*)(kp + (size_t)(f * 16 + l15) * 1024 + 32);
    acc[f] = mfma16(aq0, b0, acc[f]);
    acc[f] = mfma16(aq1, b1, acc[f]);
  }
  __syncthreads();                    // logw staged

  int nbase = n0 + w * 16 + h * 4;
  int lrow = w * 16 + h * 4;
  float mx[4] = {-INFINITY, -INFINITY, -INFINITY, -INFINITY};
  float sm[4] = {0.f, 0.f, 0.f, 0.f};
#pragma unroll
  for (int f = 0; f < 19; f++) {
    int m = f * 16 + l15;
#pragma unroll
    for (int r = 0; r < 4; r++) {
      float lw = -INFINITY;
      if (m < 300) lw = bf2f(ps[(lrow + r) * 328 + m]);
      float lg = acc[f][r] * 0.125f + lw;
      acc[f][r] = lg;
      mx[r] = fmaxf(mx[r], lg);
    }
  }
#pragma unroll
  for (int d = 1; d < 16; d <<= 1)
#pragma unroll
    for (int r = 0; r < 4; r++) mx[r] = fmaxf(mx[r], __shfl_xor(mx[r], d));
#pragma unroll
  for (int f = 0; f < 19; f++)
#pragma unroll
    for (int r = 0; r < 4; r++) {
      float p = __expf(acc[f][r] - mx[r]);
      acc[f][r] = p; sm[r] += p;
    }
#pragma unroll
  for (int d = 1; d < 16; d <<= 1)
#pragma unroll
    for (int r = 0; r < 4; r++) sm[r] += __shfl_xor(sm[r], d);
  float inv[4];
#pragma unroll
  for (int r = 0; r < 4; r++) inv[r] = 1.f / sm[r];

  __syncthreads();                    // all waves done reading logw
#pragma unroll
  for (int f = 0; f < 19; f++)
#pragma unroll
    for (int r = 0; r < 4; r++)
      ps[(lrow + r) * 344 + f * 16 + l15] = f2bf(acc[f][r]);
#pragma unroll
  for (int r = 0; r < 4; r++)         // zero pad m 304..319
    ps[(lrow + r) * 344 + 304 + l15] = 0;

  f32x4 acc2[4];
#pragma unroll
  for (int fo = 0; fo < 4; fo++) acc2[fo] = (f32x4){0.f, 0.f, 0.f, 0.f};
  const u16* vp = kvt + (size_t)g * 64 * 320 + h * 8;
#pragma unroll
  for (int ks = 0; ks < 10; ks++) {   // PV: P rows are wave-local; KVt global
    bf16x8 ap = *(const bf16x8*)&ps[(w * 16 + l15) * 344 + ks * 32 + h * 8];
#pragma unroll
    for (int fo = 0; fo < 4; fo++) {
      bf16x8 bv = *(const bf16x8*)(vp + (size_t)(fo * 16 + l15) * 320 + ks * 32);
      acc2[fo] = mfma16(ap, bv, acc2[fo]);
    }
  }
#pragma unroll
  for (int fo = 0; fo < 4; fo++) {
    int col = g * 64 + fo * 16 + l15;
    float bov = bo[col];
#pragma unroll
    for (int r = 0; r < 4; r++) {
      int row = nbase + r;
      size_t off = (size_t)row * 1024 + col;
      float v = bf2f(xr[off]) + acc2[fo][r] * inv[r] + bov;
      v = fmaxf(v, 0.f);
      if (LAST) outf[off] = v;
      else      outb[off] = f2bf(v);
    }
  }
}

// ---------------------------------------------------------------------------
extern "C" void kernel_launch(void* const* d_in, const int* in_sizes, int n_in,
                              void* d_out, int out_size, void* d_ws, size_t ws_size,
                              hipStream_t stream) {
  (void)in_sizes; (void)n_in; (void)out_size; (void)ws_size;
  const float* roi   = (const float*)d_in[0];
  const float* bbox  = (const float*)d_in[1];
  const float* Wfc1  = (const float*)d_in[2];
  const float* bfc1  = (const float*)d_in[3];
  const float* Wfc2  = (const float*)d_in[4];
  const float* bfc2  = (const float*)d_in[5];
  const float* Wpos1 = (const float*)d_in[6];
  const float* bpos1 = (const float*)d_in[7];
  const float* Wq1   = (const float*)d_in[8];
  const float* bq1   = (const float*)d_in[9];
  const float* Wk1   = (const float*)d_in[10];
  const float* bk1   = (const float*)d_in[11];
  const float* Wo1   = (const float*)d_in[12];
  const float* bo1   = (const float*)d_in[13];
  const float* Wpos2 = (const float*)d_in[14];
  const float* bpos2 = (const float*)d_in[15];
  const float* Wq2   = (const float*)d_in[16];
  const float* bq2   = (const float*)d_in[17];
  const float* Wk2   = (const float*)d_in[18];
  const float* bk2   = (const float*)d_in[19];
  const float* Wo2   = (const float*)d_in[20];
  const float* bo2   = (const float*)d_in[21];

  char* ws = (char*)d_ws;                       // ---- workspace arena ----
  u16*  Wfc1_t = (u16*)(ws + 102760448);        //  25,690,112
  u16*  Wfc2_t = (u16*)(ws + 128450560);        //   2,097,152 each
  u16*  Wq1_t  = (u16*)(ws + 130547712);
  u16*  Wk1_t  = (u16*)(ws + 132644864);
  u16*  Wq2_t  = (u16*)(ws + 134742016);
  u16*  Wk2_t  = (u16*)(ws + 136839168);
  u16*  Wo1_b  = (u16*)(ws + 138936320);
  u16*  Wo2_b  = (u16*)(ws + 141033472);
  float* Pp    = (float*)(ws + 143134720);      //  67,108,864 (splitK=4)
  u16*  xb_f   = (u16*)(ws + 243798016);        //   8,388,608 (fc out, bf16)
  u16*  xb_a   = (u16*)(ws + 252186624);        //   8,388,608 (attn out, bf16)
  u16*  q_b    = (u16*)(ws + 260575232);        //   8,388,608
  u16*  k_b    = (u16*)(ws + 268963840);        //     614,400
  u16*  kvt_b  = (u16*)(ws + 269578240);        //     655,360
  u16*  logw1  = (u16*)(ws + 270233600);        //  41,943,040
  u16*  logw2  = (u16*)(ws + 312176640);        //  41,943,040 (end 354,119,680)

  // 1. prep: Wfc1 transpose only (the sole gemm8p dependency)
  prep_kernel<<<12544, 256, 0, stream>>>(Wfc1, Wfc1_t);
  // 2. fc1 splitK=4 (reads fp32 roi directly; cvt_pk staging)
  gemm8p<<<256, 512, 0, stream>>>(roi, Wfc1_t, Pp);
  // 3. reduce (bf16 out) || pos tables || small-weight prep
  {
    RPArgs p;
    p.P = Pp; p.bias = bfc1; p.xb = xb_f;
    p.bbox = bbox;
    p.Wpos1 = Wpos1; p.Wpos2 = Wpos2;
    p.bpos1 = bpos1; p.bpos2 = bpos2;
    p.logw1 = logw1; p.logw2 = logw2;
    p.Wo1 = Wo1; p.Wo1_b = Wo1_b;
    p.Wo2 = Wo2; p.Wo2_b = Wo2_b;
    p.wsrc[0] = Wfc2; p.wdst[0] = Wfc2_t;
    p.wsrc[1] = Wq1;  p.wdst[1] = Wq1_t;
    p.wsrc[2] = Wk1;  p.wdst[2] = Wk1_t;
    p.wsrc[3] = Wq2;  p.wdst[3] = Wq2_t;
    p.wsrc[4] = Wk2;  p.wdst[4] = Wk2_t;
    reduce_pos_kernel<<<12288, 256, 0, stream>>>(p);
  }
  // ---- layer 1 ----
  {
    GDesc q  = {xb_f,  Wq1_t, bq1, q_b,   4096, 1024, 1024, 1024, 8};
    GDesc kk = {xb_f,  Wk1_t, bk1, k_b,    300, 1024, 1024, 1024, 8};
    GDesc kv = {Wo1_b, xb_f,  nullptr, kvt_b, 1024, 300, 1024, 320, 3};
    gemmU<<<304, 256, 0, stream>>>(q, kk, kv, 256, 280);
  }
  attn_kernel<false><<<dim3(64, 16), 256, 0, stream>>>(q_b, k_b, kvt_b, logw1, xb_f, bo1, nullptr, xb_a);

  // ---- layer 2 ----
  {
    GDesc fc = {xb_a, Wfc2_t, bfc2, xb_f, 4096, 1024, 1024, 1024, 8};
    gemmU<<<256, 256, 0, stream>>>(fc, fc, fc, 256, 256);
  }
  {
    GDesc q  = {xb_f,  Wq2_t, bq2, q_b,   4096, 1024, 1024, 1024, 8};
    GDesc kk = {xb_f,  Wk2_t, bk2, k_b,    300, 1024, 1024, 1024, 8};
    GDesc kv = {Wo2_b, xb_f,  nullptr, kvt_b, 1024, 300, 1024, 320, 3};
    gemmU<<<304, 256, 0, stream>>>(q, kk, kv, 256, 280);
  }
  attn_kernel<true><<<dim3(64, 16), 256, 0, stream>>>(q_b, k_b, kvt_b, logw2, xb_f, bo2, (float*)d_out, nullptr);
}

// Round 16
// 368.356 us; speedup vs baseline: 1.0789x; 1.0238x over previous
//
#include <hip/hip_runtime.h>

// ============================================================================
// FastRCNN Relation FC Head, MI355X round 16.
// vs round 15 (377.1us, best): split-K partials stored as BF16 (was fp32) -
// saves 67MB of HBM round-trip (gemm8p epilogue write + reduce read).
// Error budget: 4 partials x 2^-9 x 0.5sigma ~ 0.002 << 0.09 threshold.
// Everything else byte-identical to round 15.  Workspace: 354 MB.
// ============================================================================

using bf16x8 = __attribute__((ext_vector_type(8))) short;
using f32x4  = __attribute__((ext_vector_type(4))) float;
typedef unsigned short u16;
typedef unsigned int   u32;

#define DEV __device__ __forceinline__

DEV u32 cvtpk(float lo, float hi) {          // 2x fp32 -> packed bf16 (1 instr)
  u32 r;
  asm("v_cvt_pk_bf16_f32 %0, %1, %2" : "=v"(r) : "v"(lo), "v"(hi));
  return r;
}
DEV u16 f2bf(float f) { return (u16)cvtpk(f, f); }
DEV float bf2f(u16 h) { return __uint_as_float(((u32)h) << 16); }

DEV f32x4 mfma16(bf16x8 a, bf16x8 b, f32x4 c) {
  return __builtin_amdgcn_mfma_f32_16x16x32_bf16(a, b, c, 0, 0, 0);
}
DEV void gload16(const u16* g, u16* l) {
  __builtin_amdgcn_global_load_lds((const __attribute__((address_space(1))) void*)g,
                                   (__attribute__((address_space(3))) void*)l, 16, 0, 0);
}

DEV void fsincos(float x, float* s, float* c) {
  float r = x * 0.15915494309189535f;   // revolutions, exact-identity reduction
  r -= rintf(r);
  float a = r * 6.283185307179586f;
  *s = __sinf(a); *c = __cosf(a);
}

__constant__ float C100D[8] = {100.f, 42.16965034285822f, 17.78279410038923f,
                               7.498942093324559f, 3.1622776601683795f,
                               1.333521432163324f, 0.5623413251903491f,
                               0.23713737056616552f};

// ---------------------------------------------------------------------------
// prep: Wfc1 transpose+convert ONLY (12544 blocks of 32x32 tiles).
// ---------------------------------------------------------------------------
__global__ __launch_bounds__(256) void prep_kernel(const float* __restrict__ Wfc1,
                                                   u16* __restrict__ Wfc1_t) {
  __shared__ float tp[32][36];
  int b = blockIdx.x, tid = threadIdx.x;
  const int R = 12544, C = 1024;
  int r0 = (b >> 5) * 32, c0 = (b & 31) * 32;
  {                                             // 32x32 vectorized transpose
    int r = tid >> 3, c4 = (tid & 7) * 4;
    float4 v = *(const float4*)(Wfc1 + (size_t)(r0 + r) * C + c0 + c4);
    *(float4*)&tp[r][c4] = v;
  }
  __syncthreads();
  {
    int c = tid >> 3, r4 = (tid & 7) * 4;
    int2 v;
    v.x = (int)cvtpk(tp[r4 + 0][c], tp[r4 + 1][c]);
    v.y = (int)cvtpk(tp[r4 + 2][c], tp[r4 + 3][c]);
    *(int2*)(Wfc1_t + (size_t)(c0 + c) * R + r0 + r4) = v;
  }
}

// ---------------------------------------------------------------------------
// fc1: 256x256-tile, BK=64, 512 threads, splitK=4 (r11 schedule, frozen).
// Partials written as BF16.
// ---------------------------------------------------------------------------
__global__ __launch_bounds__(512, 2) void gemm8p(
    const float* __restrict__ A, const u16* __restrict__ Bt,
    u16* __restrict__ P) {
  const int K = 12544;                 // 4 splits x 49 tiles x BK=64
  __shared__ u16 lds[65536];           // 2 buf x (A 32KB + B 32KB) = 128 KB
  int tid = threadIdx.x;
  int w = tid >> 6, l = tid & 63, h = l >> 4, l15 = l & 15;
  int wm = w >> 2, wn = w & 3;

  int b = ((blockIdx.x & 7) << 5) | (blockIdx.x >> 3);   // XCD-chunked swizzle
  int bz = b >> 6, rest = b & 63;
  int bm = (rest & 15) * 256;
  int bn = (rest >> 4) * 256;
  size_t k0 = (size_t)bz * 3136;

  int arow = tid >> 3;                      // A staging: row within chunk
  int c0 = (tid & 7) * 8;                   // col (elems)
  const float* pA0 = A + (size_t)(bm + arow) * K + k0 + c0;
  const size_t aseg = (size_t)64 * K;
  int awe = ((arow * 128 + c0 * 2) ^ ((arow & 7) << 4)) >> 1;          // elems

  int X = ((tid >> 3) & 7) << 4;
  int lb2 = (tid * 16) ^ X;
  int lr = lb2 >> 7, lc = (lb2 & 127) >> 1;
  const u16* pB = Bt + (size_t)(bn + lr) * K + k0 + lc;
  const size_t o64 = (size_t)64 * K, o128 = (size_t)128 * K, o192 = (size_t)192 * K;

  int swz = (l15 & 7) << 3;
  int xk0 = (h * 8) ^ swz;
  int xk1 = 32 ^ xk0;
  int rA = (wm * 64 + l15) * 64;
  int rB = (wn * 32 + l15) * 64;

  f32x4 acc[8][4];
#pragma unroll
  for (int i = 0; i < 8; i++)
#pragma unroll
    for (int j = 0; j < 4; j++) acc[i][j] = (f32x4){0.f, 0.f, 0.f, 0.f};

  float4 a0[4], a1[4];
  bf16x8 af[4][2], bl[2][2], bh[2][2];

#define AISSUE(kk) { _Pragma("unroll") for (int s = 0; s < 4; s++) {     \
    a0[s] = *(const float4*)(pA0 + s * aseg + (kk));                     \
    a1[s] = *(const float4*)(pA0 + s * aseg + (kk) + 4); } }
#define BISSUE_LO(WB, kk) {                                              \
    gload16(pB + (kk),        (WB) + tid * 8);                           \
    gload16(pB + o64 + (kk),  (WB) + 4096 + tid * 8); }
#define BISSUE_HI(WB, kk) {                                              \
    gload16(pB + o128 + (kk), (WB) + 8192 + tid * 8);                    \
    gload16(pB + o192 + (kk), (WB) + 12288 + tid * 8); }
#define AWRITE(WA) { _Pragma("unroll") for (int s = 0; s < 4; s++) {     \
    int4 v;                                                              \
    v.x = (int)cvtpk(a0[s].x, a0[s].y);                                  \
    v.y = (int)cvtpk(a0[s].z, a0[s].w);                                  \
    v.z = (int)cvtpk(a1[s].x, a1[s].y);                                  \
    v.w = (int)cvtpk(a1[s].z, a1[s].w);                                  \
    *(int4*)&(WA)[awe + s * 4096] = v; } }
#define READ_AF(BASE)                                                    \
  _Pragma("unroll") for (int i = 0; i < 4; i++) {                        \
    af[i][0] = *(const bf16x8*)&LA[(BASE) + rA + i * 1024 + xk0];        \
    af[i][1] = *(const bf16x8*)&LA[(BASE) + rA + i * 1024 + xk1];        \
  }
#define READ_BL {                                                        \
  _Pragma("unroll") for (int j = 0; j < 2; j++) {                        \
    bl[j][0] = *(const bf16x8*)&LB[rB + j * 1024 + xk0];                 \
    bl[j][1] = *(const bf16x8*)&LB[rB + j * 1024 + xk1]; } }
#define READ_BH {                                                        \
  _Pragma("unroll") for (int j = 0; j < 2; j++) {                        \
    bh[j][0] = *(const bf16x8*)&LB[8192 + rB + j * 1024 + xk0];          \
    bh[j][1] = *(const bf16x8*)&LB[8192 + rB + j * 1024 + xk1]; } }
#define Q_MFMA(QR, QC, BF)                                               \
  __builtin_amdgcn_s_setprio(1);                                         \
  _Pragma("unroll") for (int i = 0; i < 4; i++)                          \
    _Pragma("unroll") for (int j = 0; j < 2; j++) {                      \
      acc[(QR)*4+i][(QC)*2+j] = mfma16(af[i][0], BF[j][0], acc[(QR)*4+i][(QC)*2+j]); \
      acc[(QR)*4+i][(QC)*2+j] = mfma16(af[i][1], BF[j][1], acc[(QR)*4+i][(QC)*2+j]); \
    }                                                                    \
  __builtin_amdgcn_s_setprio(0);
#define SBAR __builtin_amdgcn_sched_barrier(0)

  AISSUE(0);
  BISSUE_LO(lds + 16384, 0);
  BISSUE_HI(lds + 16384, 0);
  AWRITE(lds);
  asm volatile("s_waitcnt vmcnt(0) lgkmcnt(0)" ::: "memory");
  __builtin_amdgcn_s_barrier();

  for (int t = 0; t < 48; t++) {
    const u16* LA = lds + (t & 1) * 32768;
    const u16* LB = LA + 16384;
    u16* WA = lds + ((t + 1) & 1) * 32768;
    u16* WB = WA + 16384;
    int ktn = (t + 1) * 64;
    AISSUE(ktn);
    asm volatile("s_waitcnt vmcnt(10) lgkmcnt(0)" ::: "memory");
    __builtin_amdgcn_s_barrier();
    SBAR;
    READ_AF(0);
    READ_BL;
    Q_MFMA(0, 0, bl);
    SBAR;
    BISSUE_LO(WB, ktn);
    asm volatile("s_waitcnt vmcnt(10)" ::: "memory");
    __builtin_amdgcn_s_barrier();
    SBAR;
    READ_BH;
    Q_MFMA(0, 1, bh);
    SBAR;
    BISSUE_HI(WB, ktn);
    READ_AF(8192);
    Q_MFMA(1, 1, bh);
    SBAR;
    Q_MFMA(1, 0, bl);
    SBAR;
    AWRITE(WA);
  }
  {  // tail tile t=48 (buf0): counted drain 2 -> 0
    const u16* LA = lds;
    const u16* LB = lds + 16384;
    asm volatile("s_waitcnt vmcnt(2) lgkmcnt(0)" ::: "memory");
    __builtin_amdgcn_s_barrier();
    SBAR;
    READ_AF(0);
    READ_BL;
    Q_MFMA(0, 0, bl);
    SBAR;
    asm volatile("s_waitcnt vmcnt(0)" ::: "memory");
    __builtin_amdgcn_s_barrier();
    SBAR;
    READ_BH;
    Q_MFMA(0, 1, bh);
    SBAR;
    READ_AF(8192);
    Q_MFMA(1, 1, bh);
    Q_MFMA(1, 0, bl);
  }
#undef AISSUE
#undef BISSUE_LO
#undef BISSUE_HI
#undef AWRITE
#undef READ_AF
#undef READ_BL
#undef READ_BH
#undef Q_MFMA
#undef SBAR

  u16* dst = P + (size_t)bz * 4096 * 1024;
#pragma unroll
  for (int qr = 0; qr < 2; qr++)
#pragma unroll
    for (int i = 0; i < 4; i++)
#pragma unroll
      for (int qc = 0; qc < 2; qc++)
#pragma unroll
        for (int j = 0; j < 2; j++) {
          int row0 = bm + qr * 128 + wm * 64 + i * 16 + h * 4;
          int col  = bn + qc * 128 + wn * 32 + j * 16 + l15;
          f32x4 v = acc[qr * 4 + i][qc * 2 + j];
#pragma unroll
          for (int r = 0; r < 4; r++)
            dst[(size_t)(row0 + r) * 1024 + col] = f2bf(v[r]);
        }
}

// ---------------------------------------------------------------------------
// reduce || pos || small-weight prep, one launch:
//  [0,2048)       fc1 split-K reduce (bf16 partials in, bf16 out)
//  [2048,6144)    pos_logw (one block per n)
//  [6144,7168)    Wo1/Wo2 fp32->bf16 converts
//  [7168,12288)   5x 1024x1024 transpose+convert (Wfc2,Wq1,Wk1,Wq2,Wk2)
// ---------------------------------------------------------------------------
struct RPArgs {
  const u16* P; const float* bias; u16* xb;
  const float* bbox;
  const float* Wpos1; const float* Wpos2;
  const float* bpos1; const float* bpos2;
  u16* logw1; u16* logw2;
  const float* Wo1; u16* Wo1_b;
  const float* Wo2; u16* Wo2_b;
  const float* wsrc[5]; u16* wdst[5];
};

__global__ __launch_bounds__(256) void reduce_pos_kernel(RPArgs p) {
  __shared__ u16 pool[18944];     // emb 64*88 | wp 32*88 | lw 2*16*328
  int tid = threadIdx.x;
  int b = blockIdx.x;
  if (b < 2048) {                 // ---- fc1 split-K reduce (bf16 in/out) ----
    const size_t MN = (size_t)4096 * 1024;
    size_t i = ((size_t)b * 256 + tid) * 8;
    size_t stride = (size_t)2048 * 256 * 8;
    for (; i < MN; i += stride) {
      bf16x8 p0 = *(const bf16x8*)(p.P + i);
      bf16x8 p1 = *(const bf16x8*)(p.P + MN + i);
      bf16x8 p2 = *(const bf16x8*)(p.P + 2 * MN + i);
      bf16x8 p3 = *(const bf16x8*)(p.P + 3 * MN + i);
      float4 bv0 = *(const float4*)(p.bias + (i & 1023));
      float4 bv1 = *(const float4*)(p.bias + (i & 1023) + 4);
      float s[8];
#pragma unroll
      for (int e = 0; e < 8; e++)
        s[e] = bf2f((u16)p0[e]) + bf2f((u16)p1[e]) +
               bf2f((u16)p2[e]) + bf2f((u16)p3[e]);
      s[0] += bv0.x; s[1] += bv0.y; s[2] += bv0.z; s[3] += bv0.w;
      s[4] += bv1.x; s[5] += bv1.y; s[6] += bv1.z; s[7] += bv1.w;
      int4 hv;
      hv.x = (int)cvtpk(s[0], s[1]); hv.y = (int)cvtpk(s[2], s[3]);
      hv.z = (int)cvtpk(s[4], s[5]); hv.w = (int)cvtpk(s[6], s[7]);
      *(int4*)(p.xb + i) = hv;
    }
    return;
  }
  if (b < 6144) {                 // ---- pos_logw ----
    u16* emb_s = pool;            // [64][88]
    u16* wp_s  = pool + 5632;     // [32][88]
    u16* lw_s  = pool + 8448;     // [2*16][328]
    int n = b - 2048;
    int w = tid >> 6, l = tid & 63, h = l >> 4, l15 = l & 15;
    for (int idx = tid; idx < 1024; idx += 256) {   // stage Wpos^T both layers
      int e = idx >> 4, c = idx & 15;               // Wpos[e][c]
      wp_s[c * 88 + e]        = f2bf(p.Wpos1[idx]);
      wp_s[(16 + c) * 88 + e] = f2bf(p.Wpos2[idx]);
    }
    float4 bn = ((const float4*)p.bbox)[n];
    float bw_n = bn.z - bn.x + 1.f, bh_n = bn.w - bn.y + 1.f;
    float cx_n = 0.5f * (bn.x + bn.z), cy_n = 0.5f * (bn.y + bn.w);
    float bps0 = p.bpos1[l15], bps1 = p.bpos2[l15];
    int pr = tid >> 2, k = tid & 3;

    for (int m0 = 0; m0 < 320; m0 += 64) {
      int m = m0 + pr;
      float4 bm = ((const float4*)p.bbox)[m];
      float v;
      if (k == 0)      v = logf(fmaxf(fabsf((cx_n - 0.5f * (bm.x + bm.z)) / bw_n), 1e-3f));
      else if (k == 1) v = logf(fmaxf(fabsf((cy_n - 0.5f * (bm.y + bm.w)) / bh_n), 1e-3f));
      else if (k == 2) v = logf(bw_n / (bm.z - bm.x + 1.f));
      else             v = logf(bh_n / (bm.w - bm.y + 1.f));
      __syncthreads();                  // protect previous tile's frag reads
#pragma unroll
      for (int tt = 0; tt < 8; tt++) {
        float s, c; fsincos(v * C100D[tt], &s, &c);
        emb_s[pr * 88 + k * 16 + tt]     = f2bf(s);
        emb_s[pr * 88 + k * 16 + 8 + tt] = f2bf(c);
      }
      __syncthreads();
      f32x4 acc0 = {0.f, 0.f, 0.f, 0.f}, acc1 = {0.f, 0.f, 0.f, 0.f};
      bf16x8 a0 = *(const bf16x8*)&emb_s[(w * 16 + l15) * 88 + h * 8];
      bf16x8 a1 = *(const bf16x8*)&emb_s[(w * 16 + l15) * 88 + 32 + h * 8];
      bf16x8 b00 = *(const bf16x8*)&wp_s[l15 * 88 + h * 8];
      bf16x8 b01 = *(const bf16x8*)&wp_s[l15 * 88 + 32 + h * 8];
      bf16x8 b10 = *(const bf16x8*)&wp_s[(16 + l15) * 88 + h * 8];
      bf16x8 b11 = *(const bf16x8*)&wp_s[(16 + l15) * 88 + 32 + h * 8];
      acc0 = mfma16(a0, b00, acc0); acc0 = mfma16(a1, b01, acc0);
      acc1 = mfma16(a0, b10, acc1); acc1 = mfma16(a1, b11, acc1);
#pragma unroll
      for (int r = 0; r < 4; r++) {
        int mm = m0 + w * 16 + h * 4 + r;
        lw_s[l15 * 328 + mm]        = f2bf(logf(fmaxf(acc0[r] + bps0, 1e-6f)));
        lw_s[(16 + l15) * 328 + mm] = f2bf(logf(fmaxf(acc1[r] + bps1, 1e-6f)));
      }
    }
    __syncthreads();
    for (int i = tid; i < 1280; i += 256) {     // 2 layers * 16 g * 40 segs
      int layer = i / 640, rest = i - layer * 640;
      int gg = rest / 40, seg = rest - gg * 40;
      bf16x8 v = *(const bf16x8*)&lw_s[(layer * 16 + gg) * 328 + seg * 8];
      u16* dst = (layer ? p.logw2 : p.logw1) + ((size_t)gg * 4096 + n) * 320 + seg * 8;
      *(bf16x8*)dst = v;
    }
    return;
  }
  if (b < 7168) {                 // ---- Wo1/Wo2 converts ----
    int b2 = b - 6144;
    const float* src = (b2 < 512) ? p.Wo1 : p.Wo2;
    u16* dst = (b2 < 512) ? p.Wo1_b : p.Wo2_b;
    size_t i = ((size_t)(b2 & 511) * 256 + tid) * 8;
    float4 a = *(const float4*)(src + i);
    float4 c = *(const float4*)(src + i + 4);
    int4 v;
    v.x = (int)cvtpk(a.x, a.y); v.y = (int)cvtpk(a.z, a.w);
    v.z = (int)cvtpk(c.x, c.y); v.w = (int)cvtpk(c.z, c.w);
    *(int4*)(dst + i) = v;
    return;
  }
  {                               // ---- 5x 1024^2 transpose+convert ----
    float (*tp)[36] = (float(*)[36])pool;
    int idx = b - 7168;
    int z = idx >> 10, rest = idx & 1023;
    const float* in = p.wsrc[z]; u16* out = p.wdst[z];
    int r0 = (rest >> 5) * 32, c0 = (rest & 31) * 32;
    {
      int r = tid >> 3, c4 = (tid & 7) * 4;
      float4 v = *(const float4*)(in + (size_t)(r0 + r) * 1024 + c0 + c4);
      *(float4*)&tp[r][c4] = v;
    }
    __syncthreads();
    {
      int c = tid >> 3, r4 = (tid & 7) * 4;
      int2 v;
      v.x = (int)cvtpk(tp[r4 + 0][c], tp[r4 + 1][c]);
      v.y = (int)cvtpk(tp[r4 + 2][c], tp[r4 + 3][c]);
      *(int2*)(out + (size_t)(c0 + c) * 1024 + r0 + r4) = v;
    }
  }
}

// ---------------------------------------------------------------------------
// gemmU: 128x128-tile BK=64 pipelined GEMM (64KB LDS -> 2 blocks/CU),
// up to 3 problems per grid.  C = A[MxK]*Bt[NxK]^T (+bias), bf16 out.
// ---------------------------------------------------------------------------
struct GDesc {
  const u16* A; const u16* Bt; const float* bias;
  u16* Cb;
  int M, N, K, ldc, nt;          // nt = #128-wide col tiles
};

__global__ __launch_bounds__(256, 2) void gemmU(GDesc g0, GDesc g1, GDesc g2,
                                                int c0, int c1) {
  __shared__ u16 lds[32768];     // 2 buf x (A 128x64 + B 128x64) bf16 = 64 KB
  GDesc g; int lb = blockIdx.x;
  if (lb < c0) { g = g0; lb = (lb & 7) * (c0 >> 3) + (lb >> 3); }  // XCD swz
  else if (lb < c1) { g = g1; lb -= c0; }
  else { g = g2; lb -= c1; }
  int bm = (lb / g.nt) * 128, bn = (lb % g.nt) * 128;
  int tid = threadIdx.x;
  int w = tid >> 6, l = tid & 63, h = l >> 4, l15 = l & 15;
  int wm = w >> 1, wn = w & 1;
  int K = g.K;

  int X = ((tid >> 3) & 7) << 4;
  int lbyte = (tid * 16) ^ X;
  int lr = lbyte >> 7, lc = (lbyte & 127) >> 1;
  const u16 *pa[4], *pb[4];
#pragma unroll
  for (int c = 0; c < 4; c++) {
    pa[c] = g.A  + (size_t)min(bm + c * 32 + lr, g.M - 1) * K + lc;
    pb[c] = g.Bt + (size_t)min(bn + c * 32 + lr, g.N - 1) * K + lc;
  }

  int swz = (l15 & 7) << 3;
  int xk0 = (h * 8) ^ swz;
  int xk1 = 32 ^ xk0;
  int rA = (wm * 64 + l15) * 64;
  int rB = (wn * 64 + l15) * 64;

  f32x4 acc[4][4];
#pragma unroll
  for (int i = 0; i < 4; i++)
#pragma unroll
    for (int j = 0; j < 4; j++) acc[i][j] = (f32x4){0.f, 0.f, 0.f, 0.f};

#define ISSUEU(W, kk)                                     \
  { gload16(pa[0] + (kk), (W) + tid * 8);                 \
    gload16(pa[1] + (kk), (W) + 2048 + tid * 8);          \
    gload16(pa[2] + (kk), (W) + 4096 + tid * 8);          \
    gload16(pa[3] + (kk), (W) + 6144 + tid * 8);          \
    gload16(pb[0] + (kk), (W) + 8192 + tid * 8);          \
    gload16(pb[1] + (kk), (W) + 10240 + tid * 8);         \
    gload16(pb[2] + (kk), (W) + 12288 + tid * 8);         \
    gload16(pb[3] + (kk), (W) + 14336 + tid * 8); }

  ISSUEU(lds, 0);
  int ktiles = K >> 6;
  for (int t = 0; t < ktiles; t++) {
    const u16* LA = lds + (t & 1) * 16384;
    const u16* LB = LA + 8192;
    u16* W = lds + ((t ^ 1) & 1) * 16384;
    if (t < ktiles - 1) {
      ISSUEU(W, (t + 1) * 64);
      asm volatile("s_waitcnt vmcnt(8)" ::: "memory");
    } else {
      asm volatile("s_waitcnt vmcnt(0)" ::: "memory");
    }
    __builtin_amdgcn_s_barrier();
    asm volatile("" ::: "memory");
    bf16x8 a[4][2], bfr[4][2];
#pragma unroll
    for (int i = 0; i < 4; i++) {
      a[i][0] = *(const bf16x8*)&LA[rA + i * 1024 + xk0];
      a[i][1] = *(const bf16x8*)&LA[rA + i * 1024 + xk1];
    }
#pragma unroll
    for (int j = 0; j < 4; j++) {
      bfr[j][0] = *(const bf16x8*)&LB[rB + j * 1024 + xk0];
      bfr[j][1] = *(const bf16x8*)&LB[rB + j * 1024 + xk1];
    }
    __builtin_amdgcn_s_setprio(1);
#pragma unroll
    for (int i = 0; i < 4; i++)
#pragma unroll
      for (int j = 0; j < 4; j++) {
        acc[i][j] = mfma16(a[i][0], bfr[j][0], acc[i][j]);
        acc[i][j] = mfma16(a[i][1], bfr[j][1], acc[i][j]);
      }
    __builtin_amdgcn_s_setprio(0);
    asm volatile("" ::: "memory");
    __builtin_amdgcn_s_barrier();
  }
#undef ISSUEU

#pragma unroll
  for (int i = 0; i < 4; i++) {
#pragma unroll
    for (int j = 0; j < 4; j++) {
      int col = bn + wn * 64 + j * 16 + l15;
      if (col >= g.ldc) continue;
      float bv = (g.bias != nullptr && col < g.N) ? g.bias[col] : 0.f;
      int row0 = bm + wm * 64 + i * 16 + h * 4;
#pragma unroll
      for (int r = 0; r < 4; r++) {
        int row = row0 + r;
        if (row >= g.M) continue;
        g.Cb[(size_t)row * g.ldc + col] = f2bf(acc[i][j][r] + bv);
      }
    }
  }
}

// ---------------------------------------------------------------------------
// fused attention per (64-row n-tile, head g).  Residual from bf16 xr.
// ---------------------------------------------------------------------------
template <bool LAST>
__global__ __launch_bounds__(256) void attn_kernel(
    const u16* __restrict__ qb, const u16* __restrict__ kb,
    const u16* __restrict__ kvt, const u16* __restrict__ logw,
    const u16* __restrict__ xr, const float* __restrict__ bo,
    float* __restrict__ outf, u16* __restrict__ outb) {
  __shared__ u16 ps[64 * 344];      // logw [64][328]; then P [64][344]
  int tid = threadIdx.x;
  int g = blockIdx.y, n0 = blockIdx.x * 64;
  int w = tid >> 6, l = tid & 63, h = l >> 4, l15 = l & 15;

  {                                 // stage logw tile (contiguous 40KB)
    const u16* src = logw + ((size_t)g * 4096 + n0) * 320;
    for (int i = tid; i < 64 * 40; i += 256) {
      int row = i / 40, seg = i - row * 40;
      *(bf16x8*)&ps[row * 328 + seg * 8] = *(const bf16x8*)(src + row * 320 + seg * 8);
    }
  }
  int nrow = n0 + w * 16 + l15;
  const u16* qp = qb + (size_t)nrow * 1024 + g * 64;
  bf16x8 aq0 = *(const bf16x8*)(qp + h * 8);
  bf16x8 aq1 = *(const bf16x8*)(qp + 32 + h * 8);

  f32x4 acc[19];
#pragma unroll
  for (int f = 0; f < 19; f++) acc[f] = (f32x4){0.f, 0.f, 0.f, 0.f};
  const u16* kp = kb + g * 64 + h * 8;
#pragma unroll
  for (int f = 0; f < 19; f++) {      // QK^T, K frags direct from global (L2)
    bf16x8 b0 = *(const bf16x8*)(kp + (size_t)(f * 16 + l15) * 1024);
    bf16x8 b1 = *(const bf16x8*)(kp + (size_t)(f * 16 + l15) * 1024 + 32);
    acc[f] = mfma16(aq0, b0, acc[f]);
    acc[f] = mfma16(aq1, b1, acc[f]);
  }
  __syncthreads();                    // logw staged

  int nbase = n0 + w * 16 + h * 4;
  int lrow = w * 16 + h * 4;
  float mx[4] = {-INFINITY, -INFINITY, -INFINITY, -INFINITY};
  float sm[4] = {0.f, 0.f, 0.f, 0.f};
#pragma unroll
  for (int f = 0; f < 19; f++) {
    int m = f * 16 + l15;
#pragma unroll
    for (int r = 0; r < 4; r++) {
      float lw = -INFINITY;
      if (m < 300) lw = bf2f(ps[(lrow + r) * 328 + m]);
      float lg = acc[f][r] * 0.125f + lw;
      acc[f][r] = lg;
      mx[r] = fmaxf(mx[r], lg);
    }
  }
#pragma unroll
  for (int d = 1; d < 16; d <<= 1)
#pragma unroll
    for (int r = 0; r < 4; r++) mx[r] = fmaxf(mx[r], __shfl_xor(mx[r], d));
#pragma unroll
  for (int f = 0; f < 19; f++)
#pragma unroll
    for (int r = 0; r < 4; r++) {
      float p = __expf(acc[f][r] - mx[r]);
      acc[f][r] = p; sm[r] += p;
    }
#pragma unroll
  for (int d = 1; d < 16; d <<= 1)
#pragma unroll
    for (int r = 0; r < 4; r++) sm[r] += __shfl_xor(sm[r], d);
  float inv[4];
#pragma unroll
  for (int r = 0; r < 4; r++) inv[r] = 1.f / sm[r];

  __syncthreads();                    // all waves done reading logw
#pragma unroll
  for (int f = 0; f < 19; f++)
#pragma unroll
    for (int r = 0; r < 4; r++)
      ps[(lrow + r) * 344 + f * 16 + l15] = f2bf(acc[f][r]);
#pragma unroll
  for (int r = 0; r < 4; r++)         // zero pad m 304..319
    ps[(lrow + r) * 344 + 304 + l15] = 0;

  f32x4 acc2[4];
#pragma unroll
  for (int fo = 0; fo < 4; fo++) acc2[fo] = (f32x4){0.f, 0.f, 0.f, 0.f};
  const u16* vp = kvt + (size_t)g * 64 * 320 + h * 8;
#pragma unroll
  for (int ks = 0; ks < 10; ks++) {   // PV: P rows are wave-local; KVt global
    bf16x8 ap = *(const bf16x8*)&ps[(w * 16 + l15) * 344 + ks * 32 + h * 8];
#pragma unroll
    for (int fo = 0; fo < 4; fo++) {
      bf16x8 bv = *(const bf16x8*)(vp + (size_t)(fo * 16 + l15) * 320 + ks * 32);
      acc2[fo] = mfma16(ap, bv, acc2[fo]);
    }
  }
#pragma unroll
  for (int fo = 0; fo < 4; fo++) {
    int col = g * 64 + fo * 16 + l15;
    float bov = bo[col];
#pragma unroll
    for (int r = 0; r < 4; r++) {
      int row = nbase + r;
      size_t off = (size_t)row * 1024 + col;
      float v = bf2f(xr[off]) + acc2[fo][r] * inv[r] + bov;
      v = fmaxf(v, 0.f);
      if (LAST) outf[off] = v;
      else      outb[off] = f2bf(v);
    }
  }
}

// ---------------------------------------------------------------------------
extern "C" void kernel_launch(void* const* d_in, const int* in_sizes, int n_in,
                              void* d_out, int out_size, void* d_ws, size_t ws_size,
                              hipStream_t stream) {
  (void)in_sizes; (void)n_in; (void)out_size; (void)ws_size;
  const float* roi   = (const float*)d_in[0];
  const float* bbox  = (const float*)d_in[1];
  const float* Wfc1  = (const float*)d_in[2];
  const float* bfc1  = (const float*)d_in[3];
  const float* Wfc2  = (const float*)d_in[4];
  const float* bfc2  = (const float*)d_in[5];
  const float* Wpos1 = (const float*)d_in[6];
  const float* bpos1 = (const float*)d_in[7];
  const float* Wq1   = (const float*)d_in[8];
  const float* bq1   = (const float*)d_in[9];
  const float* Wk1   = (const float*)d_in[10];
  const float* bk1   = (const float*)d_in[11];
  const float* Wo1   = (const float*)d_in[12];
  const float* bo1   = (const float*)d_in[13];
  const float* Wpos2 = (const float*)d_in[14];
  const float* bpos2 = (const float*)d_in[15];
  const float* Wq2   = (const float*)d_in[16];
  const float* bq2   = (const float*)d_in[17];
  const float* Wk2   = (const float*)d_in[18];
  const float* bk2   = (const float*)d_in[19];
  const float* Wo2   = (const float*)d_in[20];
  const float* bo2   = (const float*)d_in[21];

  char* ws = (char*)d_ws;                       // ---- workspace arena ----
  u16*  Wfc1_t = (u16*)(ws + 102760448);        //  25,690,112
  u16*  Wfc2_t = (u16*)(ws + 128450560);        //   2,097,152 each
  u16*  Wq1_t  = (u16*)(ws + 130547712);
  u16*  Wk1_t  = (u16*)(ws + 132644864);
  u16*  Wq2_t  = (u16*)(ws + 134742016);
  u16*  Wk2_t  = (u16*)(ws + 136839168);
  u16*  Wo1_b  = (u16*)(ws + 138936320);
  u16*  Wo2_b  = (u16*)(ws + 141033472);
  u16*  Pp     = (u16*)(ws + 143134720);        //  33,554,432 (bf16 partials)
  u16*  xb_f   = (u16*)(ws + 243798016);        //   8,388,608 (fc out, bf16)
  u16*  xb_a   = (u16*)(ws + 252186624);        //   8,388,608 (attn out, bf16)
  u16*  q_b    = (u16*)(ws + 260575232);        //   8,388,608
  u16*  k_b    = (u16*)(ws + 268963840);        //     614,400
  u16*  kvt_b  = (u16*)(ws + 269578240);        //     655,360
  u16*  logw1  = (u16*)(ws + 270233600);        //  41,943,040
  u16*  logw2  = (u16*)(ws + 312176640);        //  41,943,040 (end 354,119,680)

  // 1. prep: Wfc1 transpose only (the sole gemm8p dependency)
  prep_kernel<<<12544, 256, 0, stream>>>(Wfc1, Wfc1_t);
  // 2. fc1 splitK=4 (reads fp32 roi directly; cvt_pk staging; bf16 partials)
  gemm8p<<<256, 512, 0, stream>>>(roi, Wfc1_t, Pp);
  // 3. reduce (bf16 in/out) || pos tables || small-weight prep
  {
    RPArgs p;
    p.P = Pp; p.bias = bfc1; p.xb = xb_f;
    p.bbox = bbox;
    p.Wpos1 = Wpos1; p.Wpos2 = Wpos2;
    p.bpos1 = bpos1; p.bpos2 = bpos2;
    p.logw1 = logw1; p.logw2 = logw2;
    p.Wo1 = Wo1; p.Wo1_b = Wo1_b;
    p.Wo2 = Wo2; p.Wo2_b = Wo2_b;
    p.wsrc[0] = Wfc2; p.wdst[0] = Wfc2_t;
    p.wsrc[1] = Wq1;  p.wdst[1] = Wq1_t;
    p.wsrc[2] = Wk1;  p.wdst[2] = Wk1_t;
    p.wsrc[3] = Wq2;  p.wdst[3] = Wq2_t;
    p.wsrc[4] = Wk2;  p.wdst[4] = Wk2_t;
    reduce_pos_kernel<<<12288, 256, 0, stream>>>(p);
  }
  // ---- layer 1 ----
  {
    GDesc q  = {xb_f,  Wq1_t, bq1, q_b,   4096, 1024, 1024, 1024, 8};
    GDesc kk = {xb_f,  Wk1_t, bk1, k_b,    300, 1024, 1024, 1024, 8};
    GDesc kv = {Wo1_b, xb_f,  nullptr, kvt_b, 1024, 300, 1024, 320, 3};
    gemmU<<<304, 256, 0, stream>>>(q, kk, kv, 256, 280);
  }
  attn_kernel<false><<<dim3(64, 16), 256, 0, stream>>>(q_b, k_b, kvt_b, logw1, xb_f, bo1, nullptr, xb_a);

  // ---- layer 2 ----
  {
    GDesc fc = {xb_a, Wfc2_t, bfc2, xb_f, 4096, 1024, 1024, 1024, 8};
    gemmU<<<256, 256, 0, stream>>>(fc, fc, fc, 256, 256);
  }
  {
    GDesc q  = {xb_f,  Wq2_t, bq2, q_b,   4096, 1024, 1024, 1024, 8};
    GDesc kk = {xb_f,  Wk2_t, bk2, k_b,    300, 1024, 1024, 1024, 8};
    GDesc kv = {Wo2_b, xb_f,  nullptr, kvt_b, 1024, 300, 1024, 320, 3};
    gemmU<<<304, 256, 0, stream>>>(q, kk, kv, 256, 280);
  }
  attn_kernel<true><<<dim3(64, 16), 256, 0, stream>>>(q_b, k_b, kvt_b, logw2, xb_f, bo2, (float*)d_out, nullptr);
}